// Round 7
// baseline (244.315 us; speedup 1.0000x reference)
//
#include <hip/hip_runtime.h>
#include <math.h>

#define BB 8
#define NN 4096
#define MM 2048
#define CC 256
#define CBD 128

typedef __attribute__((ext_vector_type(8))) short s16x8;
typedef __attribute__((ext_vector_type(8))) _Float16 f16x8;
typedef __attribute__((ext_vector_type(4))) float f32x4;
typedef __attribute__((ext_vector_type(16))) float f32x16;
typedef unsigned short u16;
typedef unsigned int u32;

__device__ __forceinline__ u16 f2bf(float f) {
    union { float f; u32 u; } v; v.f = f;
    u32 r = v.u + 0x7fffu + ((v.u >> 16) & 1u);
    return (u16)(r >> 16);
}
__device__ __forceinline__ float bf2f(u16 h) {
    union { u32 u; float f; } v; v.u = ((u32)h) << 16; return v.f;
}
__device__ __forceinline__ u16 f2h(float f) {
    union { _Float16 h; u16 u; } v; v.h = (_Float16)f; return v.u;
}
__device__ __forceinline__ u32 asu(float f) {
    union { float f; u32 u; } v; v.f = f; return v.u;
}
// pack two f32 -> packed bf16 (truncate): low16 = lo, high16 = hi
__device__ __forceinline__ u32 pkbf(float lo, float hi) {
    return __builtin_amdgcn_perm(asu(hi), asu(lo), 0x07060302u);
}

#define MFMA(a, b, c)    __builtin_amdgcn_mfma_f32_16x16x32_bf16(a, b, c, 0, 0, 0)
#define MFMA32(a, b, c)  __builtin_amdgcn_mfma_f32_32x32x16_bf16(a, b, c, 0, 0, 0)
#define MFMA32F(a, b, c) __builtin_amdgcn_mfma_f32_32x32x16_f16(a, b, c, 0, 0, 0)

__device__ __forceinline__ void gload_lds16(const u16* g, u16* l) {
    __builtin_amdgcn_global_load_lds(
        (const __attribute__((address_space(1))) void*)g,
        (__attribute__((address_space(3))) void*)l, 16, 0, 0);
}

// --------------------------------------------- split + transpose weights
__global__ __launch_bounds__(256) void k_split_w(
    const float* __restrict__ wt, const float* __restrict__ wp,
    const float* __restrict__ wg, const float* __restrict__ wo,
    u16* wth, u16* wtl, u16* wph, u16* wpl, u16* wgh, u16* wgl, u16* wot) {
    int e = blockIdx.x * 256 + threadIdx.x;
    int m = blockIdx.y;
    if (m < 3) {
        const float* src = m == 0 ? wt : (m == 1 ? wp : wg);
        u16* oh = m == 0 ? wth : (m == 1 ? wph : wgh);
        u16* ol = m == 0 ? wtl : (m == 1 ? wpl : wgl);
        int r = e >> 7, c = e & 127;          // src [256][128]
        float f = src[e];
        u16 hi = f2bf(f);
        oh[c * 256 + r] = hi;
        ol[c * 256 + r] = f2bf(f - bf2f(hi));
    } else {
        int r = e >> 8, c = e & 255;          // src [128][256]
        wot[c * 128 + r] = f2bf(wo[e]);
    }
}

// --------------------- single-pass fused split + theta/phi/g projection
// Projection math unchanged (x/W hi-lo bf16, fp32 acc). OUTPUT format:
// theta & phi now stored as SINGLE fp16 (11 mantissa bits, enough for a
// one-pass f16 QK^T in k_attn; replaces bf16 hi+lo 3-pass). g unchanged
// (bf16, PV perm). All outputs staged via LDS for coalesced s16x8 runs.
__global__ __launch_bounds__(256) void k_proj(
    const float* __restrict__ x,
    const u16* __restrict__ wth, const u16* __restrict__ wtl,
    const u16* __restrict__ wph, const u16* __restrict__ wpl,
    const u16* __restrict__ wgh,
    u16* __restrict__ th, u16* __restrict__ ph, u16* __restrict__ gt) {
    __shared__ u16 S[31232];                 // 62464 B (main-loop dominates)
    const int THH = 0, PHH = 17408, GL = 26112;
    u16* sxh = S;
    u16* sxl = S + 2560;
    u16* sw  = S + 5120;
    int tid = threadIdx.x;
    int w = tid >> 6, lane = tid & 63, q = lane >> 4, li = lane & 15;
    int r0 = blockIdx.x * 64;
    int wr2 = (w >> 1) * 32, wcc = (w & 1) * 64;
    const u16* Ws[5] = {wth, wtl, wph, wpl, wgh};

    f32x4 aT[2][4], aP[2][4], aG[2][4];
#pragma unroll
    for (int i = 0; i < 2; i++)
#pragma unroll
        for (int j = 0; j < 4; j++) {
            aT[i][j] = (f32x4)0.f; aP[i][j] = (f32x4)0.f; aG[i][j] = (f32x4)0.f;
        }

    for (int kc = 0; kc < 8; kc++) {
        {   // stage x fp32 -> hi/lo bf16 (64 rows x 32 k)
            int row = tid >> 2, seg = tid & 3;
            const float* xp = &x[(size_t)(r0 + row) * 256 + kc * 32 + seg * 8];
            float4 v0 = ((const float4*)xp)[0];
            float4 v1 = ((const float4*)xp)[1];
            float vv[8] = {v0.x, v0.y, v0.z, v0.w, v1.x, v1.y, v1.z, v1.w};
            u16 hh[8], ll[8];
#pragma unroll
            for (int t = 0; t < 8; t++) {
                hh[t] = f2bf(vv[t]);
                ll[t] = f2bf(vv[t] - bf2f(hh[t]));
            }
            *(s16x8*)&sxh[row * 40 + seg * 8] = *(s16x8*)&hh[0];
            *(s16x8*)&sxl[row * 40 + seg * 8] = *(s16x8*)&ll[0];
        }
#pragma unroll
        for (int u = 0; u < 10; u++) {  // stage 5 weight tiles (128 cols x 32 k)
            int mat = u >> 1;
            int col = (u & 1) * 64 + (tid >> 2), ch = tid & 3;
            s16x8 v = *(const s16x8*)&Ws[mat][(size_t)col * 256 + kc * 32 + ch * 8];
            *(s16x8*)&sw[mat * 5120 + col * 40 + ch * 8] = v;
        }
        __syncthreads();

        s16x8 ah[2], al[2];
#pragma unroll
        for (int i = 0; i < 2; i++) {
            ah[i] = *(const s16x8*)&sxh[(wr2 + i * 16 + li) * 40 + q * 8];
            al[i] = *(const s16x8*)&sxl[(wr2 + i * 16 + li) * 40 + q * 8];
        }
#pragma unroll
        for (int j = 0; j < 4; j++) {
            int col = wcc + j * 16 + li;
            s16x8 bth = *(const s16x8*)&sw[0 * 5120 + col * 40 + q * 8];
            s16x8 btl = *(const s16x8*)&sw[1 * 5120 + col * 40 + q * 8];
            s16x8 bph = *(const s16x8*)&sw[2 * 5120 + col * 40 + q * 8];
            s16x8 bpl = *(const s16x8*)&sw[3 * 5120 + col * 40 + q * 8];
            s16x8 bgh = *(const s16x8*)&sw[4 * 5120 + col * 40 + q * 8];
#pragma unroll
            for (int i = 0; i < 2; i++) {
                aT[i][j] = MFMA(ah[i], bth, aT[i][j]);
                aT[i][j] = MFMA(al[i], bth, aT[i][j]);
                aT[i][j] = MFMA(ah[i], btl, aT[i][j]);
                aP[i][j] = MFMA(ah[i], bph, aP[i][j]);
                aP[i][j] = MFMA(al[i], bph, aP[i][j]);
                aP[i][j] = MFMA(ah[i], bpl, aP[i][j]);
                aG[i][j] = MFMA(ah[i], bgh, aG[i][j]);
                aG[i][j] = MFMA(al[i], bgh, aG[i][j]);
            }
        }
        __syncthreads();
    }

    // ---- epilogue: stage outputs in LDS, then coalesced stores ----
#pragma unroll
    for (int i = 0; i < 2; i++)
#pragma unroll
        for (int j = 0; j < 4; j++) {
            int col = wcc + j * 16 + li;
#pragma unroll
            for (int reg = 0; reg < 4; reg++) {   // theta -> fp16
                int row = wr2 + i * 16 + q * 4 + reg;
                S[THH + row * 136 + col] = f2h(aT[i][j][reg]);
            }
#pragma unroll
            for (int pr = 0; pr < 2; pr++) {      // pooled phi (fp16) / g (bf16)
                int ml = (wr2 >> 1) + i * 8 + q * 2 + pr;   // 0..31
                float vp = fmaxf(aP[i][j][pr * 2], aP[i][j][pr * 2 + 1]);
                S[PHH + ml * 136 + col] = f2h(vp);
                float vg = fmaxf(aG[i][j][pr * 2], aG[i][j][pr * 2 + 1]);
                int ml2 = (ml & ~12) | ((ml & 4) << 1) | ((ml & 8) >> 1);  // PV perm
                S[GL + col * 40 + ml2] = f2bf(vg);
            }
        }
    __syncthreads();

    // th: 64 rows x 128 cols fp16, 16-lane 256 B runs
#pragma unroll
    for (int p2 = 0; p2 < 4; p2++) {
        int u2 = tid + p2 * 256;
        int row = u2 >> 4, chk = u2 & 15;
        size_t gb = (size_t)(r0 + row) * 128 + chk * 8;
        *(s16x8*)&th[gb] = *(const s16x8*)&S[THH + row * 136 + chk * 8];
    }
    // ph: 32 mrows x 128 cols fp16, 32 B per lane contiguous
    {
        int row = tid >> 3, chk = tid & 7;
        size_t gb = (size_t)((r0 >> 1) + row) * 128 + chk * 16;
        *(s16x8*)&ph[gb]     = *(const s16x8*)&S[PHH + row * 136 + chk * 16];
        *(s16x8*)&ph[gb + 8] = *(const s16x8*)&S[PHH + row * 136 + chk * 16 + 8];
    }
    // gt: [b][col][mi] -- 32 contiguous mi (64 B) per col, perm pre-applied
    {
        int col = tid >> 1, half = tid & 1;
        int b = r0 >> 12;
        int base = (r0 >> 1) & 2047;              // multiple of 32
        size_t gb = (size_t)b * (128 * 2048) + (size_t)col * 2048 + base + half * 16;
        *(s16x8*)&gt[gb]     = *(const s16x8*)&S[GL + col * 40 + half * 16];
        *(s16x8*)&gt[gb + 8] = *(const s16x8*)&S[GL + col * 40 + half * 16 + 8];
    }
}

// ------------------------------------------------------- flash attention
// 32 q/wave, split-K x4 (s-interleaved: 4 sibling blocks share theta rows
// in L2; 1024 blocks = exactly 4/CU at 34.8 KB LDS -- one clean round).
// QK^T is ONE fp16 MFMA pass (theta/phi stored fp16 by k_proj): S-phase
// MFMA 48->16 and LDS reads halved vs the bf16 hi/lo 3-pass. PV stays
// bf16 (P<=e^20 under deferred rescale would overflow fp16). Round-0
// proven sync structure; tree-max + deferred rescale + setprio kept.
__global__ __launch_bounds__(256, 4) void k_attn(
    const u16* __restrict__ th, const u16* __restrict__ ph,
    const u16* __restrict__ gt, u16* __restrict__ ot,
    float* __restrict__ Mv, float* __restrict__ Lv) {
    __shared__ u16 smem[17408];          // 34816 B (epilogue needs 128x136)
    u16* skh = smem;                     // 64 x 128 fp16, chunk16 ^= row&7
    u16* sg  = smem + 8192;              // 128 x 64 bf16, chunk16 ^= row&7
    int tid = threadIdx.x, w = tid >> 6, lane = tid & 63;
    int q = lane & 31, b = lane >> 5;
    int bb = blockIdx.y;
    int s = blockIdx.x & 3;              // interleaved: quads share theta
    int qt = blockIdx.x >> 2;
    int n0 = qt * 128;
    int row128 = w * 32 + q;
    size_t qrow = ((size_t)bb * 4096 + n0 + row128) * 128;

    f16x8 Qf[8];
#pragma unroll
    for (int ks = 0; ks < 8; ks++)
        Qf[ks] = *(const f16x8*)&th[qrow + ks * 16 + b * 8];

    float mrow = -INFINITY, lrow = 0.f;
    f32x16 o[4];
#pragma unroll
    for (int c = 0; c < 4; c++) o[c] = (f32x16)0.f;

    int r_hi = lane >> 4, c_hi = lane & 15;
    int r_lo = lane >> 3, c_lo = lane & 7;
    int k0 = s * 512;

    for (int kt = 0; kt < 8; kt++) {
        int m0 = k0 + kt * 64;
        if (kt) __syncthreads();
#pragma unroll
        for (int jj = 0; jj < 4; jj++) {
            int r = w * 16 + jj * 4 + r_hi;
            int gc = c_hi ^ (r & 7);
            size_t ga = (((size_t)(bb * 2048 + m0 + r)) << 7) + gc * 8;
            gload_lds16(&ph[ga], &skh[(w * 16 + jj * 4) << 7]);
            int r2 = w * 32 + jj * 8 + r_lo;
            int gc2 = c_lo ^ (r2 & 7);
            size_t ga2 = (size_t)bb * (128 * 2048) + (size_t)r2 * 2048 + m0 + gc2 * 8;
            gload_lds16(&gt[ga2], &sg[(w * 32 + jj * 8) << 6]);
        }
        __syncthreads();

        // S^T = phi . theta^T : single fp16 pass. D[key][query], col = q
        f32x16 S[2];
        S[0] = (f32x16)0.f; S[1] = (f32x16)0.f;
        __builtin_amdgcn_s_setprio(1);
#pragma unroll
        for (int ks = 0; ks < 8; ks++) {
            int off0 = (q << 7) + (((ks * 2 + b) ^ (q & 7)) << 3);
            int r1 = 32 + q;
            int off1 = (r1 << 7) + (((ks * 2 + b) ^ (r1 & 7)) << 3);
            f16x8 a0 = *(const f16x8*)&skh[off0];
            f16x8 a1 = *(const f16x8*)&skh[off1];
            S[0] = MFMA32F(a0, Qf[ks], S[0]);
            S[1] = MFMA32F(a1, Qf[ks], S[1]);
        }
        __builtin_amdgcn_s_setprio(0);

        // tree max (depth 5) + cross-half shuffle
        float t0[8];
#pragma unroll
        for (int r = 0; r < 8; r++)
            t0[r] = fmaxf(fmaxf(S[0][r], S[0][r + 8]),
                          fmaxf(S[1][r], S[1][r + 8]));
        float u0 = fmaxf(t0[0], t0[1]), u1 = fmaxf(t0[2], t0[3]);
        float u2 = fmaxf(t0[4], t0[5]), u3 = fmaxf(t0[6], t0[7]);
        float vmax = fmaxf(fmaxf(u0, u1), fmaxf(u2, u3));
        vmax = fmaxf(vmax, __shfl_xor(vmax, 32, 64));

        // deferred rescale (THR=20: P <= e^20, l <= 512*e^20 -- f32 safe)
        if (!__all(vmax - mrow <= 20.f)) {
            float nm = fmaxf(mrow, vmax);
            float alph = __expf(mrow - nm);
            mrow = nm;
            lrow *= alph;
#pragma unroll
            for (int c = 0; c < 4; c++)
#pragma unroll
                for (int r = 0; r < 16; r++) o[c][r] *= alph;
        }
        float rs0 = 0.f, rs1 = 0.f, rs2 = 0.f, rs3 = 0.f;
#pragma unroll
        for (int r = 0; r < 4; r++) {
            float p00 = __expf(S[0][r] - mrow);      S[0][r] = p00;      rs0 += p00;
            float p01 = __expf(S[0][r + 4] - mrow);  S[0][r + 4] = p01;  rs1 += p01;
            float p02 = __expf(S[0][r + 8] - mrow);  S[0][r + 8] = p02;  rs2 += p02;
            float p03 = __expf(S[0][r + 12] - mrow); S[0][r + 12] = p03; rs3 += p03;
            float p10 = __expf(S[1][r] - mrow);      S[1][r] = p10;      rs0 += p10;
            float p11 = __expf(S[1][r + 4] - mrow);  S[1][r + 4] = p11;  rs1 += p11;
            float p12 = __expf(S[1][r + 8] - mrow);  S[1][r + 8] = p12;  rs2 += p12;
            float p13 = __expf(S[1][r + 12] - mrow); S[1][r + 12] = p13; rs3 += p13;
        }
        float rs = (rs0 + rs1) + (rs2 + rs3);
        rs += __shfl_xor(rs, 32, 64);
        lrow += rs;

        // P @ V: B-fragments packed straight from S D-regs (no LDS!)
        __builtin_amdgcn_s_setprio(1);
#pragma unroll
        for (int t = 0; t < 4; t++) {
            int half = t >> 1, base = (t & 1) * 8;
            s16x8 Pf;
            u32* pf = (u32*)&Pf;
#pragma unroll
            for (int r2 = 0; r2 < 4; r2++)
                pf[r2] = pkbf(S[half][base + 2 * r2], S[half][base + 2 * r2 + 1]);
#pragma unroll
            for (int c = 0; c < 4; c++) {
                int ch = c * 32 + q;
                int off = (ch << 6) + (((t * 2 + b) ^ (ch & 7)) << 3);
                s16x8 gv = *(const s16x8*)&sg[off];
                o[c] = MFMA32(gv, Pf, o[c]);
            }
        }
        __builtin_amdgcn_s_setprio(0);
    }
    __syncthreads();

    // epilogue: LDS transpose O^T[ch][q] -> [q][ch], store bf16 unnormalized
    u16* sc = smem;  // 128 x 136 u16 = 34816 B
#pragma unroll
    for (int c = 0; c < 4; c++)
#pragma unroll
        for (int r2 = 0; r2 < 8; r2++) {
            int ch = c * 32 + ((r2 & 1) << 1) + 8 * (r2 >> 1) + 4 * b;
            u32 pk = (u32)f2bf(o[c][2 * r2]) | ((u32)f2bf(o[c][2 * r2 + 1]) << 16);
            *(u32*)&sc[row128 * 136 + ch] = pk;
        }
    __syncthreads();
    size_t obase = ((size_t)s * 32768 + (size_t)bb * 4096 + n0) * 128;
    int rowy = tid >> 1;
#pragma unroll
    for (int j = 0; j < 8; j++) {
        int chk = (tid & 1) * 8 + j;
        s16x8 v = *(const s16x8*)&sc[rowy * 136 + chk * 8];
        *(s16x8*)&ot[obase + (size_t)rowy * 128 + chk * 8] = v;
    }
    if (b == 0) {
        int gi = s * 32768 + bb * 4096 + n0 + row128;
        Mv[gi] = mrow;
        Lv[gi] = lrow;
    }
}

// -------- output GEMM + residual + 4-way split-K combine, float4 epilogue
__global__ __launch_bounds__(256) void k_out(
    const u16* __restrict__ ot, const float* __restrict__ Mv,
    const float* __restrict__ Lv, const u16* __restrict__ wot,
    const float* __restrict__ x, float* __restrict__ out) {
    __shared__ char lds_o[36864];
    u16 (*sy)[72] = (u16(*)[72])lds_o;
    u16 (*sw)[72] = (u16(*)[72])(lds_o + 18432);
    int tid = threadIdx.x, w = tid >> 6, lane = tid & 63, q = lane >> 4, li = lane & 15;
    int r0 = blockIdx.x * 128, c0 = blockIdx.y * 128;
    int wr = (w >> 1) * 64, wc = (w & 1) * 64;
    const size_t OS = (size_t)32768 * 128;

    float av[4][4];                      // [split][i]
#pragma unroll
    for (int i = 0; i < 4; i++) {
        int gr = r0 + ((tid + i * 256) >> 3);
        float m0 = Mv[gr], m1 = Mv[32768 + gr];
        float m2 = Mv[65536 + gr], m3 = Mv[98304 + gr];
        float l0 = Lv[gr], l1 = Lv[32768 + gr];
        float l2 = Lv[65536 + gr], l3 = Lv[98304 + gr];
        float Mx = fmaxf(fmaxf(m0, m1), fmaxf(m2, m3));
        float e0 = __expf(m0 - Mx), e1 = __expf(m1 - Mx);
        float e2 = __expf(m2 - Mx), e3 = __expf(m3 - Mx);
        float inv = 1.f / (l0 * e0 + l1 * e1 + l2 * e2 + l3 * e3);
        av[0][i] = e0 * inv; av[1][i] = e1 * inv;
        av[2][i] = e2 * inv; av[3][i] = e3 * inv;
    }

    f32x4 acc[4][4];
#pragma unroll
    for (int i = 0; i < 4; i++)
#pragma unroll
        for (int j = 0; j < 4; j++) acc[i][j] = (f32x4)0.f;

    for (int kc = 0; kc < 2; kc++) {
#pragma unroll
        for (int i = 0; i < 4; i++) {
            int ch = tid + i * 256;
            int r = ch >> 3, cc = (ch & 7) * 8;
            size_t ga = (size_t)(r0 + r) * 128 + kc * 64 + cc;
            s16x8 o1 = *(const s16x8*)&ot[ga];
            s16x8 o2 = *(const s16x8*)&ot[OS + ga];
            s16x8 o3 = *(const s16x8*)&ot[2 * OS + ga];
            s16x8 o4 = *(const s16x8*)&ot[3 * OS + ga];
            s16x8 yv;
#pragma unroll
            for (int e = 0; e < 8; e++)
                yv[e] = (short)f2bf(bf2f((u16)o1[e]) * av[0][i] +
                                    bf2f((u16)o2[e]) * av[1][i] +
                                    bf2f((u16)o3[e]) * av[2][i] +
                                    bf2f((u16)o4[e]) * av[3][i]);
            *(s16x8*)&sy[r][cc] = yv;
            *(s16x8*)&sw[r][cc] = *(const s16x8*)&wot[(size_t)(c0 + r) * 128 + kc * 64 + cc];
        }
        __syncthreads();
#pragma unroll
        for (int ks = 0; ks < 2; ks++)
#pragma unroll
            for (int i = 0; i < 4; i++) {
                s16x8 a = *(const s16x8*)&sy[wr + i * 16 + li][ks * 32 + q * 8];
#pragma unroll
                for (int j = 0; j < 4; j++) {
                    s16x8 bv = *(const s16x8*)&sw[wc + j * 16 + li][ks * 32 + q * 8];
                    acc[i][j] = MFMA(a, bv, acc[i][j]);
                }
            }
        __syncthreads();
    }

    // float4 epilogue via LDS transpose, 2 chunks of 64 rows
    float* sT = (float*)lds_o;           // 64 x 132 f32 = 33792 B
#pragma unroll
    for (int h = 0; h < 2; h++) {
        __syncthreads();
        if ((w >> 1) == h) {
#pragma unroll
            for (int i = 0; i < 4; i++)
#pragma unroll
                for (int j = 0; j < 4; j++)
#pragma unroll
                    for (int reg = 0; reg < 4; reg++)
                        sT[(i * 16 + q * 4 + reg) * 132 + wc + j * 16 + li] =
                            acc[i][j][reg];
        }
        __syncthreads();
#pragma unroll
        for (int p = 0; p < 8; p++) {
            int r = (tid >> 5) + p * 8;
            int c4 = (tid & 31) * 4;
            f32x4 yv = *(f32x4*)&sT[r * 132 + c4];
            size_t row = (size_t)(r0 + h * 64 + r);
            float4 xv = *(const float4*)&x[row * 256 + c0 + c4];
            float4 ov;
            ov.x = xv.x + yv[0]; ov.y = xv.y + yv[1];
            ov.z = xv.z + yv[2]; ov.w = xv.w + yv[3];
            *(float4*)&out[row * 256 + c0 + c4] = ov;
        }
    }
}

// ---------------------------------------------------------------- launch
extern "C" void kernel_launch(void* const* d_in, const int* in_sizes, int n_in,
                              void* d_out, int out_size, void* d_ws, size_t ws_size,
                              hipStream_t stream) {
    const float* x  = (const float*)d_in[0];
    const float* wt = (const float*)d_in[1];
    const float* wp = (const float*)d_in[2];
    const float* wg = (const float*)d_in[3];
    const float* wo = (const float*)d_in[4];
    float* out = (float*)d_out;

    char* p = (char*)d_ws;
    auto alloc = [&](size_t bytes) {
        char* r = p;
        p += (bytes + 255) & ~(size_t)255;
        return r;
    };
    const size_t NT = (size_t)BB * NN * CBD;   // 4194304
    const size_t NP = (size_t)BB * MM * CBD;   // 2097152

    u16* wth = (u16*)alloc(CC * CBD * 2);
    u16* wtl = (u16*)alloc(CC * CBD * 2);
    u16* wph = (u16*)alloc(CC * CBD * 2);
    u16* wpl = (u16*)alloc(CC * CBD * 2);
    u16* wgh = (u16*)alloc(CC * CBD * 2);
    u16* wgl = (u16*)alloc(CC * CBD * 2);
    u16* wot = (u16*)alloc(CC * CBD * 2);
    u16* th  = (u16*)alloc(NT * 2);            // fp16 theta
    u16* ph  = (u16*)alloc(NP * 2);            // fp16 pooled phi
    u16* gt  = (u16*)alloc(NP * 2);            // bf16 pooled g (PV perm)
    float* Mv = (float*)alloc(4 * 32768 * 4);
    float* Lv = (float*)alloc(4 * 32768 * 4);
    u16* ot  = (u16*)alloc(4 * NT * 2);        // [4][32768][128] bf16

    k_split_w<<<dim3(128, 4), 256, 0, stream>>>(wt, wp, wg, wo,
                                                wth, wtl, wph, wpl, wgh, wgl, wot);
    k_proj<<<dim3(512), 256, 0, stream>>>(x, wth, wtl, wph, wpl, wgh,
                                          th, ph, gt);
    k_attn<<<dim3(128, 8), 256, 0, stream>>>(th, ph, gt, ot, Mv, Lv);
    k_out<<<dim3(256, 2), 256, 0, stream>>>(ot, Mv, Lv, wot, x, out);
}

// Round 8
// 170.729 us; speedup vs baseline: 1.4310x; 1.4310x over previous
//
#include <hip/hip_runtime.h>
#include <math.h>

#define BB 8
#define NN 4096
#define MM 2048
#define CC 256
#define CBD 128

typedef __attribute__((ext_vector_type(8))) short s16x8;
typedef __attribute__((ext_vector_type(8))) _Float16 f16x8;
typedef __attribute__((ext_vector_type(4))) float f32x4;
typedef __attribute__((ext_vector_type(16))) float f32x16;
typedef unsigned short u16;
typedef unsigned int u32;

__device__ __forceinline__ u16 f2bf(float f) {
    union { float f; u32 u; } v; v.f = f;
    u32 r = v.u + 0x7fffu + ((v.u >> 16) & 1u);
    return (u16)(r >> 16);
}
__device__ __forceinline__ float bf2f(u16 h) {
    union { u32 u; float f; } v; v.u = ((u32)h) << 16; return v.f;
}
__device__ __forceinline__ u16 f2h(float f) {
    union { _Float16 h; u16 u; } v; v.h = (_Float16)f; return v.u;
}
__device__ __forceinline__ u32 asu(float f) {
    union { float f; u32 u; } v; v.f = f; return v.u;
}
// pack two f32 -> packed bf16 (truncate): low16 = lo, high16 = hi
__device__ __forceinline__ u32 pkbf(float lo, float hi) {
    return __builtin_amdgcn_perm(asu(hi), asu(lo), 0x07060302u);
}

#define MFMA(a, b, c)    __builtin_amdgcn_mfma_f32_16x16x32_bf16(a, b, c, 0, 0, 0)
#define MFMA32(a, b, c)  __builtin_amdgcn_mfma_f32_32x32x16_bf16(a, b, c, 0, 0, 0)
#define MFMA32F(a, b, c) __builtin_amdgcn_mfma_f32_32x32x16_f16(a, b, c, 0, 0, 0)

__device__ __forceinline__ void gload_lds16(const u16* g, u16* l) {
    __builtin_amdgcn_global_load_lds(
        (const __attribute__((address_space(1))) void*)g,
        (__attribute__((address_space(3))) void*)l, 16, 0, 0);
}

// --------------------------------------------- split + transpose weights
__global__ __launch_bounds__(256) void k_split_w(
    const float* __restrict__ wt, const float* __restrict__ wp,
    const float* __restrict__ wg, const float* __restrict__ wo,
    u16* wth, u16* wtl, u16* wph, u16* wpl, u16* wgh, u16* wgl, u16* wot) {
    int e = blockIdx.x * 256 + threadIdx.x;
    int m = blockIdx.y;
    if (m < 3) {
        const float* src = m == 0 ? wt : (m == 1 ? wp : wg);
        u16* oh = m == 0 ? wth : (m == 1 ? wph : wgh);
        u16* ol = m == 0 ? wtl : (m == 1 ? wpl : wgl);
        int r = e >> 7, c = e & 127;          // src [256][128]
        float f = src[e];
        u16 hi = f2bf(f);
        oh[c * 256 + r] = hi;
        ol[c * 256 + r] = f2bf(f - bf2f(hi));
    } else {
        int r = e >> 8, c = e & 255;          // src [128][256]
        wot[c * 128 + r] = f2bf(wo[e]);
    }
}

// --------------------- single-pass fused split + theta/phi/g projection
// Projection math unchanged (x/W hi-lo bf16, fp32 acc). OUTPUT format:
// theta & phi stored as SINGLE fp16 (11 mantissa bits -> one-pass f16
// QK^T in k_attn). g unchanged (bf16, PV perm). All outputs staged via
// LDS for coalesced s16x8 runs.
__global__ __launch_bounds__(256) void k_proj(
    const float* __restrict__ x,
    const u16* __restrict__ wth, const u16* __restrict__ wtl,
    const u16* __restrict__ wph, const u16* __restrict__ wpl,
    const u16* __restrict__ wgh,
    u16* __restrict__ th, u16* __restrict__ ph, u16* __restrict__ gt) {
    __shared__ u16 S[31232];                 // 62464 B (main-loop dominates)
    const int THH = 0, PHH = 17408, GL = 26112;
    u16* sxh = S;
    u16* sxl = S + 2560;
    u16* sw  = S + 5120;
    int tid = threadIdx.x;
    int w = tid >> 6, lane = tid & 63, q = lane >> 4, li = lane & 15;
    int r0 = blockIdx.x * 64;
    int wr2 = (w >> 1) * 32, wcc = (w & 1) * 64;
    const u16* Ws[5] = {wth, wtl, wph, wpl, wgh};

    f32x4 aT[2][4], aP[2][4], aG[2][4];
#pragma unroll
    for (int i = 0; i < 2; i++)
#pragma unroll
        for (int j = 0; j < 4; j++) {
            aT[i][j] = (f32x4)0.f; aP[i][j] = (f32x4)0.f; aG[i][j] = (f32x4)0.f;
        }

    for (int kc = 0; kc < 8; kc++) {
        {   // stage x fp32 -> hi/lo bf16 (64 rows x 32 k)
            int row = tid >> 2, seg = tid & 3;
            const float* xp = &x[(size_t)(r0 + row) * 256 + kc * 32 + seg * 8];
            float4 v0 = ((const float4*)xp)[0];
            float4 v1 = ((const float4*)xp)[1];
            float vv[8] = {v0.x, v0.y, v0.z, v0.w, v1.x, v1.y, v1.z, v1.w};
            u16 hh[8], ll[8];
#pragma unroll
            for (int t = 0; t < 8; t++) {
                hh[t] = f2bf(vv[t]);
                ll[t] = f2bf(vv[t] - bf2f(hh[t]));
            }
            *(s16x8*)&sxh[row * 40 + seg * 8] = *(s16x8*)&hh[0];
            *(s16x8*)&sxl[row * 40 + seg * 8] = *(s16x8*)&ll[0];
        }
#pragma unroll
        for (int u = 0; u < 10; u++) {  // stage 5 weight tiles (128 cols x 32 k)
            int mat = u >> 1;
            int col = (u & 1) * 64 + (tid >> 2), ch = tid & 3;
            s16x8 v = *(const s16x8*)&Ws[mat][(size_t)col * 256 + kc * 32 + ch * 8];
            *(s16x8*)&sw[mat * 5120 + col * 40 + ch * 8] = v;
        }
        __syncthreads();

        s16x8 ah[2], al[2];
#pragma unroll
        for (int i = 0; i < 2; i++) {
            ah[i] = *(const s16x8*)&sxh[(wr2 + i * 16 + li) * 40 + q * 8];
            al[i] = *(const s16x8*)&sxl[(wr2 + i * 16 + li) * 40 + q * 8];
        }
#pragma unroll
        for (int j = 0; j < 4; j++) {
            int col = wcc + j * 16 + li;
            s16x8 bth = *(const s16x8*)&sw[0 * 5120 + col * 40 + q * 8];
            s16x8 btl = *(const s16x8*)&sw[1 * 5120 + col * 40 + q * 8];
            s16x8 bph = *(const s16x8*)&sw[2 * 5120 + col * 40 + q * 8];
            s16x8 bpl = *(const s16x8*)&sw[3 * 5120 + col * 40 + q * 8];
            s16x8 bgh = *(const s16x8*)&sw[4 * 5120 + col * 40 + q * 8];
#pragma unroll
            for (int i = 0; i < 2; i++) {
                aT[i][j] = MFMA(ah[i], bth, aT[i][j]);
                aT[i][j] = MFMA(al[i], bth, aT[i][j]);
                aT[i][j] = MFMA(ah[i], btl, aT[i][j]);
                aP[i][j] = MFMA(ah[i], bph, aP[i][j]);
                aP[i][j] = MFMA(al[i], bph, aP[i][j]);
                aP[i][j] = MFMA(ah[i], bpl, aP[i][j]);
                aG[i][j] = MFMA(ah[i], bgh, aG[i][j]);
                aG[i][j] = MFMA(al[i], bgh, aG[i][j]);
            }
        }
        __syncthreads();
    }

    // ---- epilogue: stage outputs in LDS, then coalesced stores ----
#pragma unroll
    for (int i = 0; i < 2; i++)
#pragma unroll
        for (int j = 0; j < 4; j++) {
            int col = wcc + j * 16 + li;
#pragma unroll
            for (int reg = 0; reg < 4; reg++) {   // theta -> fp16
                int row = wr2 + i * 16 + q * 4 + reg;
                S[THH + row * 136 + col] = f2h(aT[i][j][reg]);
            }
#pragma unroll
            for (int pr = 0; pr < 2; pr++) {      // pooled phi (fp16) / g (bf16)
                int ml = (wr2 >> 1) + i * 8 + q * 2 + pr;   // 0..31
                float vp = fmaxf(aP[i][j][pr * 2], aP[i][j][pr * 2 + 1]);
                S[PHH + ml * 136 + col] = f2h(vp);
                float vg = fmaxf(aG[i][j][pr * 2], aG[i][j][pr * 2 + 1]);
                int ml2 = (ml & ~12) | ((ml & 4) << 1) | ((ml & 8) >> 1);  // PV perm
                S[GL + col * 40 + ml2] = f2bf(vg);
            }
        }
    __syncthreads();

    // th: 64 rows x 128 cols fp16, 16-lane 256 B runs
#pragma unroll
    for (int p2 = 0; p2 < 4; p2++) {
        int u2 = tid + p2 * 256;
        int row = u2 >> 4, chk = u2 & 15;
        size_t gb = (size_t)(r0 + row) * 128 + chk * 8;
        *(s16x8*)&th[gb] = *(const s16x8*)&S[THH + row * 136 + chk * 8];
    }
    // ph: 32 mrows x 128 cols fp16, 32 B per lane contiguous
    {
        int row = tid >> 3, chk = tid & 7;
        size_t gb = (size_t)((r0 >> 1) + row) * 128 + chk * 16;
        *(s16x8*)&ph[gb]     = *(const s16x8*)&S[PHH + row * 136 + chk * 16];
        *(s16x8*)&ph[gb + 8] = *(const s16x8*)&S[PHH + row * 136 + chk * 16 + 8];
    }
    // gt: [b][col][mi] -- 32 contiguous mi (64 B) per col, perm pre-applied
    {
        int col = tid >> 1, half = tid & 1;
        int b = r0 >> 12;
        int base = (r0 >> 1) & 2047;              // multiple of 32
        size_t gb = (size_t)b * (128 * 2048) + (size_t)col * 2048 + base + half * 16;
        *(s16x8*)&gt[gb]     = *(const s16x8*)&S[GL + col * 40 + half * 16];
        *(s16x8*)&gt[gb + 8] = *(const s16x8*)&S[GL + col * 40 + half * 16 + 8];
    }
}

// ------------------------------------------------------- flash attention
// 32 q/wave, split-K x2, s-interleaved blockIdx (pairs share theta rows
// in L2 -- round 7 proved that halving per-block key range to raise
// occupancy collapses cache locality: FETCH 41->227 MB, dur +60%).
// QK^T is ONE fp16 MFMA pass: S-phase MFMA 48->16/tile, phi staging and
// S-LDS reads halved vs bf16 hi/lo 3-pass. PV stays bf16 (P<=e^20 under
// deferred rescale would overflow fp16). Round-0 proven sync structure;
// tree-max + deferred rescale + setprio kept.
__global__ __launch_bounds__(256, 2) void k_attn(
    const u16* __restrict__ th, const u16* __restrict__ ph,
    const u16* __restrict__ gt, u16* __restrict__ ot,
    float* __restrict__ Mv, float* __restrict__ Lv) {
    __shared__ u16 smem[17408];          // 34816 B (epilogue needs 128x136)
    u16* skh = smem;                     // 64 x 128 fp16, chunk16 ^= row&7
    u16* sg  = smem + 8192;              // 128 x 64 bf16, chunk16 ^= row&7
    int tid = threadIdx.x, w = tid >> 6, lane = tid & 63;
    int q = lane & 31, b = lane >> 5;
    int bb = blockIdx.y;
    int s = blockIdx.x & 1;              // interleaved: pairs share theta
    int qt = blockIdx.x >> 1;
    int n0 = qt * 128;
    int row128 = w * 32 + q;
    size_t qrow = ((size_t)bb * 4096 + n0 + row128) * 128;

    f16x8 Qf[8];
#pragma unroll
    for (int ks = 0; ks < 8; ks++)
        Qf[ks] = *(const f16x8*)&th[qrow + ks * 16 + b * 8];

    float mrow = -INFINITY, lrow = 0.f;
    f32x16 o[4];
#pragma unroll
    for (int c = 0; c < 4; c++) o[c] = (f32x16)0.f;

    int r_hi = lane >> 4, c_hi = lane & 15;
    int r_lo = lane >> 3, c_lo = lane & 7;
    int k0 = s * 1024;

    for (int kt = 0; kt < 16; kt++) {
        int m0 = k0 + kt * 64;
        if (kt) __syncthreads();
#pragma unroll
        for (int jj = 0; jj < 4; jj++) {
            int r = w * 16 + jj * 4 + r_hi;
            int gc = c_hi ^ (r & 7);
            size_t ga = (((size_t)(bb * 2048 + m0 + r)) << 7) + gc * 8;
            gload_lds16(&ph[ga], &skh[(w * 16 + jj * 4) << 7]);
            int r2 = w * 32 + jj * 8 + r_lo;
            int gc2 = c_lo ^ (r2 & 7);
            size_t ga2 = (size_t)bb * (128 * 2048) + (size_t)r2 * 2048 + m0 + gc2 * 8;
            gload_lds16(&gt[ga2], &sg[(w * 32 + jj * 8) << 6]);
        }
        __syncthreads();

        // S^T = phi . theta^T : single fp16 pass. D[key][query], col = q
        f32x16 S[2];
        S[0] = (f32x16)0.f; S[1] = (f32x16)0.f;
        __builtin_amdgcn_s_setprio(1);
#pragma unroll
        for (int ks = 0; ks < 8; ks++) {
            int off0 = (q << 7) + (((ks * 2 + b) ^ (q & 7)) << 3);
            int r1 = 32 + q;
            int off1 = (r1 << 7) + (((ks * 2 + b) ^ (r1 & 7)) << 3);
            f16x8 a0 = *(const f16x8*)&skh[off0];
            f16x8 a1 = *(const f16x8*)&skh[off1];
            S[0] = MFMA32F(a0, Qf[ks], S[0]);
            S[1] = MFMA32F(a1, Qf[ks], S[1]);
        }
        __builtin_amdgcn_s_setprio(0);

        // tree max (depth 5) + cross-half shuffle
        float t0[8];
#pragma unroll
        for (int r = 0; r < 8; r++)
            t0[r] = fmaxf(fmaxf(S[0][r], S[0][r + 8]),
                          fmaxf(S[1][r], S[1][r + 8]));
        float u0 = fmaxf(t0[0], t0[1]), u1 = fmaxf(t0[2], t0[3]);
        float u2 = fmaxf(t0[4], t0[5]), u3 = fmaxf(t0[6], t0[7]);
        float vmax = fmaxf(fmaxf(u0, u1), fmaxf(u2, u3));
        vmax = fmaxf(vmax, __shfl_xor(vmax, 32, 64));

        // deferred rescale (THR=20: P <= e^20, l <= 1024*e^20 -- f32 safe)
        if (!__all(vmax - mrow <= 20.f)) {
            float nm = fmaxf(mrow, vmax);
            float alph = __expf(mrow - nm);
            mrow = nm;
            lrow *= alph;
#pragma unroll
            for (int c = 0; c < 4; c++)
#pragma unroll
                for (int r = 0; r < 16; r++) o[c][r] *= alph;
        }
        float rs0 = 0.f, rs1 = 0.f, rs2 = 0.f, rs3 = 0.f;
#pragma unroll
        for (int r = 0; r < 4; r++) {
            float p00 = __expf(S[0][r] - mrow);      S[0][r] = p00;      rs0 += p00;
            float p01 = __expf(S[0][r + 4] - mrow);  S[0][r + 4] = p01;  rs1 += p01;
            float p02 = __expf(S[0][r + 8] - mrow);  S[0][r + 8] = p02;  rs2 += p02;
            float p03 = __expf(S[0][r + 12] - mrow); S[0][r + 12] = p03; rs3 += p03;
            float p10 = __expf(S[1][r] - mrow);      S[1][r] = p10;      rs0 += p10;
            float p11 = __expf(S[1][r + 4] - mrow);  S[1][r + 4] = p11;  rs1 += p11;
            float p12 = __expf(S[1][r + 8] - mrow);  S[1][r + 8] = p12;  rs2 += p12;
            float p13 = __expf(S[1][r + 12] - mrow); S[1][r + 12] = p13; rs3 += p13;
        }
        float rs = (rs0 + rs1) + (rs2 + rs3);
        rs += __shfl_xor(rs, 32, 64);
        lrow += rs;

        // P @ V: B-fragments packed straight from S D-regs (no LDS!)
        __builtin_amdgcn_s_setprio(1);
#pragma unroll
        for (int t = 0; t < 4; t++) {
            int half = t >> 1, base = (t & 1) * 8;
            s16x8 Pf;
            u32* pf = (u32*)&Pf;
#pragma unroll
            for (int r2 = 0; r2 < 4; r2++)
                pf[r2] = pkbf(S[half][base + 2 * r2], S[half][base + 2 * r2 + 1]);
#pragma unroll
            for (int c = 0; c < 4; c++) {
                int ch = c * 32 + q;
                int off = (ch << 6) + (((t * 2 + b) ^ (ch & 7)) << 3);
                s16x8 gv = *(const s16x8*)&sg[off];
                o[c] = MFMA32(gv, Pf, o[c]);
            }
        }
        __builtin_amdgcn_s_setprio(0);
    }
    __syncthreads();

    // epilogue: LDS transpose O^T[ch][q] -> [q][ch], store bf16 unnormalized
    u16* sc = smem;  // 128 x 136 u16 = 34816 B
#pragma unroll
    for (int c = 0; c < 4; c++)
#pragma unroll
        for (int r2 = 0; r2 < 8; r2++) {
            int ch = c * 32 + ((r2 & 1) << 1) + 8 * (r2 >> 1) + 4 * b;
            u32 pk = (u32)f2bf(o[c][2 * r2]) | ((u32)f2bf(o[c][2 * r2 + 1]) << 16);
            *(u32*)&sc[row128 * 136 + ch] = pk;
        }
    __syncthreads();
    size_t obase = ((size_t)s * 32768 + (size_t)bb * 4096 + n0) * 128;
    int rowy = tid >> 1;
#pragma unroll
    for (int j = 0; j < 8; j++) {
        int chk = (tid & 1) * 8 + j;
        s16x8 v = *(const s16x8*)&sc[rowy * 136 + chk * 8];
        *(s16x8*)&ot[obase + (size_t)rowy * 128 + chk * 8] = v;
    }
    if (b == 0) {
        int gi = s * 32768 + bb * 4096 + n0 + row128;
        Mv[gi] = mrow;
        Lv[gi] = lrow;
    }
}

// ------------- output GEMM + residual + split-K combine, float4 epilogue
__global__ __launch_bounds__(256) void k_out(
    const u16* __restrict__ ot, const float* __restrict__ Mv,
    const float* __restrict__ Lv, const u16* __restrict__ wot,
    const float* __restrict__ x, float* __restrict__ out) {
    __shared__ char lds_o[36864];
    u16 (*sy)[72] = (u16(*)[72])lds_o;
    u16 (*sw)[72] = (u16(*)[72])(lds_o + 18432);
    int tid = threadIdx.x, w = tid >> 6, lane = tid & 63, q = lane >> 4, li = lane & 15;
    int r0 = blockIdx.x * 128, c0 = blockIdx.y * 128;
    int wr = (w >> 1) * 64, wc = (w & 1) * 64;
    const size_t OS = (size_t)32768 * 128;

    float a1v[4], a2v[4];
#pragma unroll
    for (int i = 0; i < 4; i++) {
        int gr = r0 + ((tid + i * 256) >> 3);
        float m1 = Mv[gr], m2 = Mv[32768 + gr];
        float l1 = Lv[gr], l2 = Lv[32768 + gr];
        float Mx = fmaxf(m1, m2);
        float e1 = __expf(m1 - Mx), e2 = __expf(m2 - Mx);
        float inv = 1.f / (l1 * e1 + l2 * e2);
        a1v[i] = e1 * inv;
        a2v[i] = e2 * inv;
    }

    f32x4 acc[4][4];
#pragma unroll
    for (int i = 0; i < 4; i++)
#pragma unroll
        for (int j = 0; j < 4; j++) acc[i][j] = (f32x4)0.f;

    for (int kc = 0; kc < 2; kc++) {
#pragma unroll
        for (int i = 0; i < 4; i++) {
            int ch = tid + i * 256;
            int r = ch >> 3, cc = (ch & 7) * 8;
            size_t ga = (size_t)(r0 + r) * 128 + kc * 64 + cc;
            s16x8 o1 = *(const s16x8*)&ot[ga];
            s16x8 o2 = *(const s16x8*)&ot[OS + ga];
            s16x8 yv;
#pragma unroll
            for (int e = 0; e < 8; e++)
                yv[e] = (short)f2bf(bf2f((u16)o1[e]) * a1v[i] +
                                    bf2f((u16)o2[e]) * a2v[i]);
            *(s16x8*)&sy[r][cc] = yv;
            *(s16x8*)&sw[r][cc] = *(const s16x8*)&wot[(size_t)(c0 + r) * 128 + kc * 64 + cc];
        }
        __syncthreads();
#pragma unroll
        for (int ks = 0; ks < 2; ks++)
#pragma unroll
            for (int i = 0; i < 4; i++) {
                s16x8 a = *(const s16x8*)&sy[wr + i * 16 + li][ks * 32 + q * 8];
#pragma unroll
                for (int j = 0; j < 4; j++) {
                    s16x8 bv = *(const s16x8*)&sw[wc + j * 16 + li][ks * 32 + q * 8];
                    acc[i][j] = MFMA(a, bv, acc[i][j]);
                }
            }
        __syncthreads();
    }

    // float4 epilogue via LDS transpose, 2 chunks of 64 rows
    float* sT = (float*)lds_o;           // 64 x 132 f32 = 33792 B
#pragma unroll
    for (int h = 0; h < 2; h++) {
        __syncthreads();
        if ((w >> 1) == h) {
#pragma unroll
            for (int i = 0; i < 4; i++)
#pragma unroll
                for (int j = 0; j < 4; j++)
#pragma unroll
                    for (int reg = 0; reg < 4; reg++)
                        sT[(i * 16 + q * 4 + reg) * 132 + wc + j * 16 + li] =
                            acc[i][j][reg];
        }
        __syncthreads();
#pragma unroll
        for (int p = 0; p < 8; p++) {
            int r = (tid >> 5) + p * 8;
            int c4 = (tid & 31) * 4;
            f32x4 yv = *(f32x4*)&sT[r * 132 + c4];
            size_t row = (size_t)(r0 + h * 64 + r);
            float4 xv = *(const float4*)&x[row * 256 + c0 + c4];
            float4 ov;
            ov.x = xv.x + yv[0]; ov.y = xv.y + yv[1];
            ov.z = xv.z + yv[2]; ov.w = xv.w + yv[3];
            *(float4*)&out[row * 256 + c0 + c4] = ov;
        }
    }
}

// ---------------------------------------------------------------- launch
extern "C" void kernel_launch(void* const* d_in, const int* in_sizes, int n_in,
                              void* d_out, int out_size, void* d_ws, size_t ws_size,
                              hipStream_t stream) {
    const float* x  = (const float*)d_in[0];
    const float* wt = (const float*)d_in[1];
    const float* wp = (const float*)d_in[2];
    const float* wg = (const float*)d_in[3];
    const float* wo = (const float*)d_in[4];
    float* out = (float*)d_out;

    char* p = (char*)d_ws;
    auto alloc = [&](size_t bytes) {
        char* r = p;
        p += (bytes + 255) & ~(size_t)255;
        return r;
    };
    const size_t NT = (size_t)BB * NN * CBD;   // 4194304
    const size_t NP = (size_t)BB * MM * CBD;   // 2097152

    u16* wth = (u16*)alloc(CC * CBD * 2);
    u16* wtl = (u16*)alloc(CC * CBD * 2);
    u16* wph = (u16*)alloc(CC * CBD * 2);
    u16* wpl = (u16*)alloc(CC * CBD * 2);
    u16* wgh = (u16*)alloc(CC * CBD * 2);
    u16* wgl = (u16*)alloc(CC * CBD * 2);
    u16* wot = (u16*)alloc(CC * CBD * 2);
    u16* th  = (u16*)alloc(NT * 2);            // fp16 theta
    u16* ph  = (u16*)alloc(NP * 2);            // fp16 pooled phi
    u16* gt  = (u16*)alloc(NP * 2);            // bf16 pooled g (PV perm)
    float* Mv = (float*)alloc(2 * 32768 * 4);
    float* Lv = (float*)alloc(2 * 32768 * 4);
    u16* ot  = (u16*)alloc(2 * NT * 2);        // [2][32768][128] bf16

    k_split_w<<<dim3(128, 4), 256, 0, stream>>>(wt, wp, wg, wo,
                                                wth, wtl, wph, wpl, wgh, wgl, wot);
    k_proj<<<dim3(512), 256, 0, stream>>>(x, wth, wtl, wph, wpl, wgh,
                                          th, ph, gt);
    k_attn<<<dim3(64, 8), 256, 0, stream>>>(th, ph, gt, ot, Mv, Lv);
    k_out<<<dim3(256, 2), 256, 0, stream>>>(ot, Mv, Lv, wot, x, out);
}

// Round 9
// 162.928 us; speedup vs baseline: 1.4995x; 1.0479x over previous
//
#include <hip/hip_runtime.h>
#include <math.h>

#define BB 8
#define NN 4096
#define MM 2048
#define CC 256
#define CBD 128

typedef __attribute__((ext_vector_type(8))) short s16x8;
typedef __attribute__((ext_vector_type(8))) _Float16 f16x8;
typedef __attribute__((ext_vector_type(4))) float f32x4;
typedef __attribute__((ext_vector_type(16))) float f32x16;
typedef unsigned short u16;
typedef unsigned int u32;

__device__ __forceinline__ u16 f2bf(float f) {
    union { float f; u32 u; } v; v.f = f;
    u32 r = v.u + 0x7fffu + ((v.u >> 16) & 1u);
    return (u16)(r >> 16);
}
__device__ __forceinline__ float bf2f(u16 h) {
    union { u32 u; float f; } v; v.u = ((u32)h) << 16; return v.f;
}
__device__ __forceinline__ u16 f2h(float f) {
    union { _Float16 h; u16 u; } v; v.h = (_Float16)f; return v.u;
}
__device__ __forceinline__ u32 asu(float f) {
    union { float f; u32 u; } v; v.f = f; return v.u;
}
// pack two f32 -> packed bf16 (truncate): low16 = lo, high16 = hi
__device__ __forceinline__ u32 pkbf(float lo, float hi) {
    return __builtin_amdgcn_perm(asu(hi), asu(lo), 0x07060302u);
}

#define MFMA(a, b, c)    __builtin_amdgcn_mfma_f32_16x16x32_bf16(a, b, c, 0, 0, 0)
#define MFMAF(a, b, c)   __builtin_amdgcn_mfma_f32_16x16x32_f16(a, b, c, 0, 0, 0)
#define MFMA32(a, b, c)  __builtin_amdgcn_mfma_f32_32x32x16_bf16(a, b, c, 0, 0, 0)
#define MFMA32F(a, b, c) __builtin_amdgcn_mfma_f32_32x32x16_f16(a, b, c, 0, 0, 0)

__device__ __forceinline__ void gload_lds16(const u16* g, u16* l) {
    __builtin_amdgcn_global_load_lds(
        (const __attribute__((address_space(1))) void*)g,
        (__attribute__((address_space(3))) void*)l, 16, 0, 0);
}

// --------------------------------------------- convert + transpose weights
// wt/wp/wg -> fp16 transposed [128][256]; wo -> bf16 transposed [256][128].
__global__ __launch_bounds__(256) void k_split_w(
    const float* __restrict__ wt, const float* __restrict__ wp,
    const float* __restrict__ wg, const float* __restrict__ wo,
    u16* wtf, u16* wpf, u16* wgf, u16* wot) {
    int e = blockIdx.x * 256 + threadIdx.x;
    int m = blockIdx.y;
    if (m < 3) {
        const float* src = m == 0 ? wt : (m == 1 ? wp : wg);
        u16* of = m == 0 ? wtf : (m == 1 ? wpf : wgf);
        int r = e >> 7, c = e & 127;          // src [256][128]
        of[c * 256 + r] = f2h(src[e]);
    } else {
        int r = e >> 8, c = e & 255;          // src [128][256]
        wot[c * 128 + r] = f2bf(wo[e]);
    }
}

// --------------------- single-pass fused theta/phi/g projection (fp16)
// x and the three projection weights are converted to SINGLE fp16 and the
// three GEMMs run one f16 MFMA pass each (was bf16 hi/lo: 8 passes).
// Error: per-term 2^-10*|x.w|, over K=256 ~1.4e-3 abs on theta/phi/g
// (0.1% rel) -- an order below the accepted fp16 QK^T rounding.
// Outputs IDENTICAL format to round 8: th fp16, ph fp16, gt bf16 (PV perm),
// all staged via LDS for coalesced s16x8 stores.
__global__ __launch_bounds__(256) void k_proj(
    const float* __restrict__ x,
    const u16* __restrict__ wtf, const u16* __restrict__ wpf,
    const u16* __restrict__ wgf,
    u16* __restrict__ th, u16* __restrict__ ph, u16* __restrict__ gt) {
    // flat LDS pool, aliased:
    //   main loop: sxf [64][40] @0, sw [3][128][40] @2560
    //   epilogue:  thh [64][136] @0, phh [32][136] @8704, g [128][40] @13056
    __shared__ u16 S[18176];                 // 36352 B
    const int THH = 0, PHH = 8704, GL = 13056;
    u16* sxf = S;
    u16* sw  = S + 2560;
    int tid = threadIdx.x;
    int w = tid >> 6, lane = tid & 63, q = lane >> 4, li = lane & 15;
    int r0 = blockIdx.x * 64;
    int wr2 = (w >> 1) * 32, wcc = (w & 1) * 64;
    const u16* Ws[3] = {wtf, wpf, wgf};

    f32x4 aT[2][4], aP[2][4], aG[2][4];
#pragma unroll
    for (int i = 0; i < 2; i++)
#pragma unroll
        for (int j = 0; j < 4; j++) {
            aT[i][j] = (f32x4)0.f; aP[i][j] = (f32x4)0.f; aG[i][j] = (f32x4)0.f;
        }

    for (int kc = 0; kc < 8; kc++) {
        {   // stage x fp32 -> fp16 (64 rows x 32 k)
            int row = tid >> 2, seg = tid & 3;
            const float* xp = &x[(size_t)(r0 + row) * 256 + kc * 32 + seg * 8];
            float4 v0 = ((const float4*)xp)[0];
            float4 v1 = ((const float4*)xp)[1];
            u16 hh[8];
            hh[0] = f2h(v0.x); hh[1] = f2h(v0.y);
            hh[2] = f2h(v0.z); hh[3] = f2h(v0.w);
            hh[4] = f2h(v1.x); hh[5] = f2h(v1.y);
            hh[6] = f2h(v1.z); hh[7] = f2h(v1.w);
            *(s16x8*)&sxf[row * 40 + seg * 8] = *(s16x8*)&hh[0];
        }
#pragma unroll
        for (int u = 0; u < 6; u++) {  // stage 3 weight tiles (128 cols x 32 k)
            int mat = u >> 1;
            int col = (u & 1) * 64 + (tid >> 2), ch = tid & 3;
            s16x8 v = *(const s16x8*)&Ws[mat][(size_t)col * 256 + kc * 32 + ch * 8];
            *(s16x8*)&sw[mat * 5120 + col * 40 + ch * 8] = v;
        }
        __syncthreads();

        f16x8 af[2];
#pragma unroll
        for (int i = 0; i < 2; i++)
            af[i] = *(const f16x8*)&sxf[(wr2 + i * 16 + li) * 40 + q * 8];
#pragma unroll
        for (int j = 0; j < 4; j++) {
            int col = wcc + j * 16 + li;
            f16x8 bt = *(const f16x8*)&sw[0 * 5120 + col * 40 + q * 8];
            f16x8 bp = *(const f16x8*)&sw[1 * 5120 + col * 40 + q * 8];
            f16x8 bg = *(const f16x8*)&sw[2 * 5120 + col * 40 + q * 8];
#pragma unroll
            for (int i = 0; i < 2; i++) {
                aT[i][j] = MFMAF(af[i], bt, aT[i][j]);
                aP[i][j] = MFMAF(af[i], bp, aP[i][j]);
                aG[i][j] = MFMAF(af[i], bg, aG[i][j]);
            }
        }
        __syncthreads();
    }

    // ---- epilogue: stage outputs in LDS, then coalesced stores ----
#pragma unroll
    for (int i = 0; i < 2; i++)
#pragma unroll
        for (int j = 0; j < 4; j++) {
            int col = wcc + j * 16 + li;
#pragma unroll
            for (int reg = 0; reg < 4; reg++) {   // theta -> fp16
                int row = wr2 + i * 16 + q * 4 + reg;
                S[THH + row * 136 + col] = f2h(aT[i][j][reg]);
            }
#pragma unroll
            for (int pr = 0; pr < 2; pr++) {      // pooled phi (fp16) / g (bf16)
                int ml = (wr2 >> 1) + i * 8 + q * 2 + pr;   // 0..31
                float vp = fmaxf(aP[i][j][pr * 2], aP[i][j][pr * 2 + 1]);
                S[PHH + ml * 136 + col] = f2h(vp);
                float vg = fmaxf(aG[i][j][pr * 2], aG[i][j][pr * 2 + 1]);
                int ml2 = (ml & ~12) | ((ml & 4) << 1) | ((ml & 8) >> 1);  // PV perm
                S[GL + col * 40 + ml2] = f2bf(vg);
            }
        }
    __syncthreads();

    // th: 64 rows x 128 cols fp16, 16-lane 256 B runs
#pragma unroll
    for (int p2 = 0; p2 < 4; p2++) {
        int u2 = tid + p2 * 256;
        int row = u2 >> 4, chk = u2 & 15;
        size_t gb = (size_t)(r0 + row) * 128 + chk * 8;
        *(s16x8*)&th[gb] = *(const s16x8*)&S[THH + row * 136 + chk * 8];
    }
    // ph: 32 mrows x 128 cols fp16, 32 B per lane contiguous
    {
        int row = tid >> 3, chk = tid & 7;
        size_t gb = (size_t)((r0 >> 1) + row) * 128 + chk * 16;
        *(s16x8*)&ph[gb]     = *(const s16x8*)&S[PHH + row * 136 + chk * 16];
        *(s16x8*)&ph[gb + 8] = *(const s16x8*)&S[PHH + row * 136 + chk * 16 + 8];
    }
    // gt: [b][col][mi] -- 32 contiguous mi (64 B) per col, perm pre-applied
    {
        int col = tid >> 1, half = tid & 1;
        int b = r0 >> 12;
        int base = (r0 >> 1) & 2047;              // multiple of 32
        size_t gb = (size_t)b * (128 * 2048) + (size_t)col * 2048 + base + half * 16;
        *(s16x8*)&gt[gb]     = *(const s16x8*)&S[GL + col * 40 + half * 16];
        *(s16x8*)&gt[gb + 8] = *(const s16x8*)&S[GL + col * 40 + half * 16 + 8];
    }
}

// ------------------------------------------------------- flash attention
// 32 q/wave, split-K x2, s-interleaved blockIdx (pairs share theta rows
// in L2 -- round 7 proved that halving per-block key range to raise
// occupancy collapses cache locality: FETCH 41->227 MB, dur +60%).
// QK^T is ONE fp16 MFMA pass: S-phase MFMA 48->16/tile, phi staging and
// S-LDS reads halved vs bf16 hi/lo 3-pass. PV stays bf16 (P<=e^20 under
// deferred rescale would overflow fp16). Round-0 proven sync structure;
// tree-max + deferred rescale + setprio kept.  (byte-identical to round 8)
__global__ __launch_bounds__(256, 2) void k_attn(
    const u16* __restrict__ th, const u16* __restrict__ ph,
    const u16* __restrict__ gt, u16* __restrict__ ot,
    float* __restrict__ Mv, float* __restrict__ Lv) {
    __shared__ u16 smem[17408];          // 34816 B (epilogue needs 128x136)
    u16* skh = smem;                     // 64 x 128 fp16, chunk16 ^= row&7
    u16* sg  = smem + 8192;              // 128 x 64 bf16, chunk16 ^= row&7
    int tid = threadIdx.x, w = tid >> 6, lane = tid & 63;
    int q = lane & 31, b = lane >> 5;
    int bb = blockIdx.y;
    int s = blockIdx.x & 1;              // interleaved: pairs share theta
    int qt = blockIdx.x >> 1;
    int n0 = qt * 128;
    int row128 = w * 32 + q;
    size_t qrow = ((size_t)bb * 4096 + n0 + row128) * 128;

    f16x8 Qf[8];
#pragma unroll
    for (int ks = 0; ks < 8; ks++)
        Qf[ks] = *(const f16x8*)&th[qrow + ks * 16 + b * 8];

    float mrow = -INFINITY, lrow = 0.f;
    f32x16 o[4];
#pragma unroll
    for (int c = 0; c < 4; c++) o[c] = (f32x16)0.f;

    int r_hi = lane >> 4, c_hi = lane & 15;
    int r_lo = lane >> 3, c_lo = lane & 7;
    int k0 = s * 1024;

    for (int kt = 0; kt < 16; kt++) {
        int m0 = k0 + kt * 64;
        if (kt) __syncthreads();
#pragma unroll
        for (int jj = 0; jj < 4; jj++) {
            int r = w * 16 + jj * 4 + r_hi;
            int gc = c_hi ^ (r & 7);
            size_t ga = (((size_t)(bb * 2048 + m0 + r)) << 7) + gc * 8;
            gload_lds16(&ph[ga], &skh[(w * 16 + jj * 4) << 7]);
            int r2 = w * 32 + jj * 8 + r_lo;
            int gc2 = c_lo ^ (r2 & 7);
            size_t ga2 = (size_t)bb * (128 * 2048) + (size_t)r2 * 2048 + m0 + gc2 * 8;
            gload_lds16(&gt[ga2], &sg[(w * 32 + jj * 8) << 6]);
        }
        __syncthreads();

        // S^T = phi . theta^T : single fp16 pass. D[key][query], col = q
        f32x16 S[2];
        S[0] = (f32x16)0.f; S[1] = (f32x16)0.f;
        __builtin_amdgcn_s_setprio(1);
#pragma unroll
        for (int ks = 0; ks < 8; ks++) {
            int off0 = (q << 7) + (((ks * 2 + b) ^ (q & 7)) << 3);
            int r1 = 32 + q;
            int off1 = (r1 << 7) + (((ks * 2 + b) ^ (r1 & 7)) << 3);
            f16x8 a0 = *(const f16x8*)&skh[off0];
            f16x8 a1 = *(const f16x8*)&skh[off1];
            S[0] = MFMA32F(a0, Qf[ks], S[0]);
            S[1] = MFMA32F(a1, Qf[ks], S[1]);
        }
        __builtin_amdgcn_s_setprio(0);

        // tree max (depth 5) + cross-half shuffle
        float t0[8];
#pragma unroll
        for (int r = 0; r < 8; r++)
            t0[r] = fmaxf(fmaxf(S[0][r], S[0][r + 8]),
                          fmaxf(S[1][r], S[1][r + 8]));
        float u0 = fmaxf(t0[0], t0[1]), u1 = fmaxf(t0[2], t0[3]);
        float u2 = fmaxf(t0[4], t0[5]), u3 = fmaxf(t0[6], t0[7]);
        float vmax = fmaxf(fmaxf(u0, u1), fmaxf(u2, u3));
        vmax = fmaxf(vmax, __shfl_xor(vmax, 32, 64));

        // deferred rescale (THR=20: P <= e^20, l <= 1024*e^20 -- f32 safe)
        if (!__all(vmax - mrow <= 20.f)) {
            float nm = fmaxf(mrow, vmax);
            float alph = __expf(mrow - nm);
            mrow = nm;
            lrow *= alph;
#pragma unroll
            for (int c = 0; c < 4; c++)
#pragma unroll
                for (int r = 0; r < 16; r++) o[c][r] *= alph;
        }
        float rs0 = 0.f, rs1 = 0.f, rs2 = 0.f, rs3 = 0.f;
#pragma unroll
        for (int r = 0; r < 4; r++) {
            float p00 = __expf(S[0][r] - mrow);      S[0][r] = p00;      rs0 += p00;
            float p01 = __expf(S[0][r + 4] - mrow);  S[0][r + 4] = p01;  rs1 += p01;
            float p02 = __expf(S[0][r + 8] - mrow);  S[0][r + 8] = p02;  rs2 += p02;
            float p03 = __expf(S[0][r + 12] - mrow); S[0][r + 12] = p03; rs3 += p03;
            float p10 = __expf(S[1][r] - mrow);      S[1][r] = p10;      rs0 += p10;
            float p11 = __expf(S[1][r + 4] - mrow);  S[1][r + 4] = p11;  rs1 += p11;
            float p12 = __expf(S[1][r + 8] - mrow);  S[1][r + 8] = p12;  rs2 += p12;
            float p13 = __expf(S[1][r + 12] - mrow); S[1][r + 12] = p13; rs3 += p13;
        }
        float rs = (rs0 + rs1) + (rs2 + rs3);
        rs += __shfl_xor(rs, 32, 64);
        lrow += rs;

        // P @ V: B-fragments packed straight from S D-regs (no LDS!)
        __builtin_amdgcn_s_setprio(1);
#pragma unroll
        for (int t = 0; t < 4; t++) {
            int half = t >> 1, base = (t & 1) * 8;
            s16x8 Pf;
            u32* pf = (u32*)&Pf;
#pragma unroll
            for (int r2 = 0; r2 < 4; r2++)
                pf[r2] = pkbf(S[half][base + 2 * r2], S[half][base + 2 * r2 + 1]);
#pragma unroll
            for (int c = 0; c < 4; c++) {
                int ch = c * 32 + q;
                int off = (ch << 6) + (((t * 2 + b) ^ (ch & 7)) << 3);
                s16x8 gv = *(const s16x8*)&sg[off];
                o[c] = MFMA32(gv, Pf, o[c]);
            }
        }
        __builtin_amdgcn_s_setprio(0);
    }
    __syncthreads();

    // epilogue: LDS transpose O^T[ch][q] -> [q][ch], store bf16 unnormalized
    u16* sc = smem;  // 128 x 136 u16 = 34816 B
#pragma unroll
    for (int c = 0; c < 4; c++)
#pragma unroll
        for (int r2 = 0; r2 < 8; r2++) {
            int ch = c * 32 + ((r2 & 1) << 1) + 8 * (r2 >> 1) + 4 * b;
            u32 pk = (u32)f2bf(o[c][2 * r2]) | ((u32)f2bf(o[c][2 * r2 + 1]) << 16);
            *(u32*)&sc[row128 * 136 + ch] = pk;
        }
    __syncthreads();
    size_t obase = ((size_t)s * 32768 + (size_t)bb * 4096 + n0) * 128;
    int rowy = tid >> 1;
#pragma unroll
    for (int j = 0; j < 8; j++) {
        int chk = (tid & 1) * 8 + j;
        s16x8 v = *(const s16x8*)&sc[rowy * 136 + chk * 8];
        *(s16x8*)&ot[obase + (size_t)rowy * 128 + chk * 8] = v;
    }
    if (b == 0) {
        int gi = s * 32768 + bb * 4096 + n0 + row128;
        Mv[gi] = mrow;
        Lv[gi] = lrow;
    }
}

// ------------- output GEMM + residual + split-K combine, float4 epilogue
__global__ __launch_bounds__(256) void k_out(
    const u16* __restrict__ ot, const float* __restrict__ Mv,
    const float* __restrict__ Lv, const u16* __restrict__ wot,
    const float* __restrict__ x, float* __restrict__ out) {
    __shared__ char lds_o[36864];
    u16 (*sy)[72] = (u16(*)[72])lds_o;
    u16 (*sw)[72] = (u16(*)[72])(lds_o + 18432);
    int tid = threadIdx.x, w = tid >> 6, lane = tid & 63, q = lane >> 4, li = lane & 15;
    int r0 = blockIdx.x * 128, c0 = blockIdx.y * 128;
    int wr = (w >> 1) * 64, wc = (w & 1) * 64;
    const size_t OS = (size_t)32768 * 128;

    float a1v[4], a2v[4];
#pragma unroll
    for (int i = 0; i < 4; i++) {
        int gr = r0 + ((tid + i * 256) >> 3);
        float m1 = Mv[gr], m2 = Mv[32768 + gr];
        float l1 = Lv[gr], l2 = Lv[32768 + gr];
        float Mx = fmaxf(m1, m2);
        float e1 = __expf(m1 - Mx), e2 = __expf(m2 - Mx);
        float inv = 1.f / (l1 * e1 + l2 * e2);
        a1v[i] = e1 * inv;
        a2v[i] = e2 * inv;
    }

    f32x4 acc[4][4];
#pragma unroll
    for (int i = 0; i < 4; i++)
#pragma unroll
        for (int j = 0; j < 4; j++) acc[i][j] = (f32x4)0.f;

    for (int kc = 0; kc < 2; kc++) {
#pragma unroll
        for (int i = 0; i < 4; i++) {
            int ch = tid + i * 256;
            int r = ch >> 3, cc = (ch & 7) * 8;
            size_t ga = (size_t)(r0 + r) * 128 + kc * 64 + cc;
            s16x8 o1 = *(const s16x8*)&ot[ga];
            s16x8 o2 = *(const s16x8*)&ot[OS + ga];
            s16x8 yv;
#pragma unroll
            for (int e = 0; e < 8; e++)
                yv[e] = (short)f2bf(bf2f((u16)o1[e]) * a1v[i] +
                                    bf2f((u16)o2[e]) * a2v[i]);
            *(s16x8*)&sy[r][cc] = yv;
            *(s16x8*)&sw[r][cc] = *(const s16x8*)&wot[(size_t)(c0 + r) * 128 + kc * 64 + cc];
        }
        __syncthreads();
#pragma unroll
        for (int ks = 0; ks < 2; ks++)
#pragma unroll
            for (int i = 0; i < 4; i++) {
                s16x8 a = *(const s16x8*)&sy[wr + i * 16 + li][ks * 32 + q * 8];
#pragma unroll
                for (int j = 0; j < 4; j++) {
                    s16x8 bv = *(const s16x8*)&sw[wc + j * 16 + li][ks * 32 + q * 8];
                    acc[i][j] = MFMA(a, bv, acc[i][j]);
                }
            }
        __syncthreads();
    }

    // float4 epilogue via LDS transpose, 2 chunks of 64 rows
    float* sT = (float*)lds_o;           // 64 x 132 f32 = 33792 B
#pragma unroll
    for (int h = 0; h < 2; h++) {
        __syncthreads();
        if ((w >> 1) == h) {
#pragma unroll
            for (int i = 0; i < 4; i++)
#pragma unroll
                for (int j = 0; j < 4; j++)
#pragma unroll
                    for (int reg = 0; reg < 4; reg++)
                        sT[(i * 16 + q * 4 + reg) * 132 + wc + j * 16 + li] =
                            acc[i][j][reg];
        }
        __syncthreads();
#pragma unroll
        for (int p = 0; p < 8; p++) {
            int r = (tid >> 5) + p * 8;
            int c4 = (tid & 31) * 4;
            f32x4 yv = *(f32x4*)&sT[r * 132 + c4];
            size_t row = (size_t)(r0 + h * 64 + r);
            float4 xv = *(const float4*)&x[row * 256 + c0 + c4];
            float4 ov;
            ov.x = xv.x + yv[0]; ov.y = xv.y + yv[1];
            ov.z = xv.z + yv[2]; ov.w = xv.w + yv[3];
            *(float4*)&out[row * 256 + c0 + c4] = ov;
        }
    }
}

// ---------------------------------------------------------------- launch
extern "C" void kernel_launch(void* const* d_in, const int* in_sizes, int n_in,
                              void* d_out, int out_size, void* d_ws, size_t ws_size,
                              hipStream_t stream) {
    const float* x  = (const float*)d_in[0];
    const float* wt = (const float*)d_in[1];
    const float* wp = (const float*)d_in[2];
    const float* wg = (const float*)d_in[3];
    const float* wo = (const float*)d_in[4];
    float* out = (float*)d_out;

    char* p = (char*)d_ws;
    auto alloc = [&](size_t bytes) {
        char* r = p;
        p += (bytes + 255) & ~(size_t)255;
        return r;
    };
    const size_t NT = (size_t)BB * NN * CBD;   // 4194304
    const size_t NP = (size_t)BB * MM * CBD;   // 2097152

    u16* wtf = (u16*)alloc(CC * CBD * 2);      // fp16 W_theta^T
    u16* wpf = (u16*)alloc(CC * CBD * 2);      // fp16 W_phi^T
    u16* wgf = (u16*)alloc(CC * CBD * 2);      // fp16 W_g^T
    u16* wot = (u16*)alloc(CC * CBD * 2);      // bf16 W_out^T
    u16* th  = (u16*)alloc(NT * 2);            // fp16 theta
    u16* ph  = (u16*)alloc(NP * 2);            // fp16 pooled phi
    u16* gt  = (u16*)alloc(NP * 2);            // bf16 pooled g (PV perm)
    float* Mv = (float*)alloc(2 * 32768 * 4);
    float* Lv = (float*)alloc(2 * 32768 * 4);
    u16* ot  = (u16*)alloc(2 * NT * 2);        // [2][32768][128] bf16

    k_split_w<<<dim3(128, 4), 256, 0, stream>>>(wt, wp, wg, wo,
                                                wtf, wpf, wgf, wot);
    k_proj<<<dim3(512), 256, 0, stream>>>(x, wtf, wpf, wgf, th, ph, gt);
    k_attn<<<dim3(64, 8), 256, 0, stream>>>(th, ph, gt, ot, Mv, Lv);
    k_out<<<dim3(256, 2), 256, 0, stream>>>(ot, Mv, Lv, wot, x, out);
}

// Round 10
// 159.041 us; speedup vs baseline: 1.5362x; 1.0244x over previous
//
#include <hip/hip_runtime.h>
#include <math.h>

#define BB 8
#define NN 4096
#define MM 2048
#define CC 256
#define CBD 128

typedef __attribute__((ext_vector_type(8))) short s16x8;
typedef __attribute__((ext_vector_type(8))) _Float16 f16x8;
typedef __attribute__((ext_vector_type(4))) float f32x4;
typedef __attribute__((ext_vector_type(16))) float f32x16;
typedef unsigned short u16;
typedef unsigned int u32;

__device__ __forceinline__ u16 f2bf(float f) {
    union { float f; u32 u; } v; v.f = f;
    u32 r = v.u + 0x7fffu + ((v.u >> 16) & 1u);
    return (u16)(r >> 16);
}
__device__ __forceinline__ float bf2f(u16 h) {
    union { u32 u; float f; } v; v.u = ((u32)h) << 16; return v.f;
}
__device__ __forceinline__ u16 f2h(float f) {
    union { _Float16 h; u16 u; } v; v.h = (_Float16)f; return v.u;
}
__device__ __forceinline__ u32 asu(float f) {
    union { float f; u32 u; } v; v.f = f; return v.u;
}
// pack two f32 -> packed bf16 (truncate): low16 = lo, high16 = hi
__device__ __forceinline__ u32 pkbf(float lo, float hi) {
    return __builtin_amdgcn_perm(asu(hi), asu(lo), 0x07060302u);
}

#define MFMA(a, b, c)    __builtin_amdgcn_mfma_f32_16x16x32_bf16(a, b, c, 0, 0, 0)
#define MFMAF(a, b, c)   __builtin_amdgcn_mfma_f32_16x16x32_f16(a, b, c, 0, 0, 0)
#define MFMA32(a, b, c)  __builtin_amdgcn_mfma_f32_32x32x16_bf16(a, b, c, 0, 0, 0)
#define MFMA32F(a, b, c) __builtin_amdgcn_mfma_f32_32x32x16_f16(a, b, c, 0, 0, 0)

__device__ __forceinline__ void gload_lds16(const u16* g, u16* l) {
    __builtin_amdgcn_global_load_lds(
        (const __attribute__((address_space(1))) void*)g,
        (__attribute__((address_space(3))) void*)l, 16, 0, 0);
}

// --------------------------------------------- convert + transpose weights
// wt/wp/wg -> fp16 transposed [128][256]; wo -> bf16 transposed [256][128].
__global__ __launch_bounds__(256) void k_split_w(
    const float* __restrict__ wt, const float* __restrict__ wp,
    const float* __restrict__ wg, const float* __restrict__ wo,
    u16* wtf, u16* wpf, u16* wgf, u16* wot) {
    int e = blockIdx.x * 256 + threadIdx.x;
    int m = blockIdx.y;
    if (m < 3) {
        const float* src = m == 0 ? wt : (m == 1 ? wp : wg);
        u16* of = m == 0 ? wtf : (m == 1 ? wpf : wgf);
        int r = e >> 7, c = e & 127;          // src [256][128]
        of[c * 256 + r] = f2h(src[e]);
    } else {
        int r = e >> 8, c = e & 255;          // src [128][256]
        wot[c * 128 + r] = f2bf(wo[e]);
    }
}

// --------------------- single-pass fused theta/phi/g projection (fp16)
// One f16 MFMA pass per GEMM. This round: kc+1's x/weight global loads
// are issued into REGISTERS between the two barriers (overlapping the
// MFMA phase) -- plain __syncthreads double-buffer-via-regs, no counted
// vmcnt. Outputs identical format: th fp16, ph fp16, gt bf16 (PV perm).
__global__ __launch_bounds__(256) void k_proj(
    const float* __restrict__ x,
    const u16* __restrict__ wtf, const u16* __restrict__ wpf,
    const u16* __restrict__ wgf,
    u16* __restrict__ th, u16* __restrict__ ph, u16* __restrict__ gt) {
    // flat LDS pool, aliased:
    //   main loop: sxf [64][40] @0, sw [3][128][40] @2560
    //   epilogue:  thh [64][136] @0, phh [32][136] @8704, g [128][40] @13056
    __shared__ u16 S[18176];                 // 36352 B
    const int THH = 0, PHH = 8704, GL = 13056;
    u16* sxf = S;
    u16* sw  = S + 2560;
    int tid = threadIdx.x;
    int w = tid >> 6, lane = tid & 63, q = lane >> 4, li = lane & 15;
    int r0 = blockIdx.x * 64;
    int wr2 = (w >> 1) * 32, wcc = (w & 1) * 64;
    const u16* Ws[3] = {wtf, wpf, wgf};

    f32x4 aT[2][4], aP[2][4], aG[2][4];
#pragma unroll
    for (int i = 0; i < 2; i++)
#pragma unroll
        for (int j = 0; j < 4; j++) {
            aT[i][j] = (f32x4)0.f; aP[i][j] = (f32x4)0.f; aG[i][j] = (f32x4)0.f;
        }

    int xrow = tid >> 2, xseg = tid & 3;
    const float* xbase = &x[(size_t)(r0 + xrow) * 256 + xseg * 8];
    int wcol = tid >> 2, wch = tid & 3;

    // prologue: load kc=0 into regs
    float4 cx0 = ((const float4*)xbase)[0];
    float4 cx1 = ((const float4*)xbase)[1];
    s16x8 cw[6];
#pragma unroll
    for (int u = 0; u < 6; u++)
        cw[u] = *(const s16x8*)&Ws[u >> 1][(size_t)((u & 1) * 64 + wcol) * 256 + wch * 8];

    for (int kc = 0; kc < 8; kc++) {
        {   // regs -> LDS (fp16 convert for x)
            u16 hh[8];
            hh[0] = f2h(cx0.x); hh[1] = f2h(cx0.y);
            hh[2] = f2h(cx0.z); hh[3] = f2h(cx0.w);
            hh[4] = f2h(cx1.x); hh[5] = f2h(cx1.y);
            hh[6] = f2h(cx1.z); hh[7] = f2h(cx1.w);
            *(s16x8*)&sxf[xrow * 40 + xseg * 8] = *(s16x8*)&hh[0];
#pragma unroll
            for (int u = 0; u < 6; u++)
                *(s16x8*)&sw[(u >> 1) * 5120 + ((u & 1) * 64 + wcol) * 40 + wch * 8] = cw[u];
        }
        __syncthreads();

        // prefetch kc+1 into regs -- overlaps the MFMA phase below
        float4 nx0, nx1; s16x8 nw[6];
        if (kc < 7) {
            const float* xp = xbase + (kc + 1) * 32;
            nx0 = ((const float4*)xp)[0];
            nx1 = ((const float4*)xp)[1];
#pragma unroll
            for (int u = 0; u < 6; u++)
                nw[u] = *(const s16x8*)&Ws[u >> 1][(size_t)((u & 1) * 64 + wcol) * 256 +
                                                  (kc + 1) * 32 + wch * 8];
        }

        f16x8 af[2];
#pragma unroll
        for (int i = 0; i < 2; i++)
            af[i] = *(const f16x8*)&sxf[(wr2 + i * 16 + li) * 40 + q * 8];
#pragma unroll
        for (int j = 0; j < 4; j++) {
            int col = wcc + j * 16 + li;
            f16x8 bt = *(const f16x8*)&sw[0 * 5120 + col * 40 + q * 8];
            f16x8 bp = *(const f16x8*)&sw[1 * 5120 + col * 40 + q * 8];
            f16x8 bg = *(const f16x8*)&sw[2 * 5120 + col * 40 + q * 8];
#pragma unroll
            for (int i = 0; i < 2; i++) {
                aT[i][j] = MFMAF(af[i], bt, aT[i][j]);
                aP[i][j] = MFMAF(af[i], bp, aP[i][j]);
                aG[i][j] = MFMAF(af[i], bg, aG[i][j]);
            }
        }
        __syncthreads();
        if (kc < 7) {
            cx0 = nx0; cx1 = nx1;
#pragma unroll
            for (int u = 0; u < 6; u++) cw[u] = nw[u];
        }
    }

    // ---- epilogue: stage outputs in LDS, then coalesced stores ----
#pragma unroll
    for (int i = 0; i < 2; i++)
#pragma unroll
        for (int j = 0; j < 4; j++) {
            int col = wcc + j * 16 + li;
#pragma unroll
            for (int reg = 0; reg < 4; reg++) {   // theta -> fp16
                int row = wr2 + i * 16 + q * 4 + reg;
                S[THH + row * 136 + col] = f2h(aT[i][j][reg]);
            }
#pragma unroll
            for (int pr = 0; pr < 2; pr++) {      // pooled phi (fp16) / g (bf16)
                int ml = (wr2 >> 1) + i * 8 + q * 2 + pr;   // 0..31
                float vp = fmaxf(aP[i][j][pr * 2], aP[i][j][pr * 2 + 1]);
                S[PHH + ml * 136 + col] = f2h(vp);
                float vg = fmaxf(aG[i][j][pr * 2], aG[i][j][pr * 2 + 1]);
                int ml2 = (ml & ~12) | ((ml & 4) << 1) | ((ml & 8) >> 1);  // PV perm
                S[GL + col * 40 + ml2] = f2bf(vg);
            }
        }
    __syncthreads();

    // th: 64 rows x 128 cols fp16, 16-lane 256 B runs
#pragma unroll
    for (int p2 = 0; p2 < 4; p2++) {
        int u2 = tid + p2 * 256;
        int row = u2 >> 4, chk = u2 & 15;
        size_t gb = (size_t)(r0 + row) * 128 + chk * 8;
        *(s16x8*)&th[gb] = *(const s16x8*)&S[THH + row * 136 + chk * 8];
    }
    // ph: 32 mrows x 128 cols fp16, 32 B per lane contiguous
    {
        int row = tid >> 3, chk = tid & 7;
        size_t gb = (size_t)((r0 >> 1) + row) * 128 + chk * 16;
        *(s16x8*)&ph[gb]     = *(const s16x8*)&S[PHH + row * 136 + chk * 16];
        *(s16x8*)&ph[gb + 8] = *(const s16x8*)&S[PHH + row * 136 + chk * 16 + 8];
    }
    // gt: [b][col][mi] -- 32 contiguous mi (64 B) per col, perm pre-applied
    {
        int col = tid >> 1, half = tid & 1;
        int b = r0 >> 12;
        int base = (r0 >> 1) & 2047;              // multiple of 32
        size_t gb = (size_t)b * (128 * 2048) + (size_t)col * 2048 + base + half * 16;
        *(s16x8*)&gt[gb]     = *(const s16x8*)&S[GL + col * 40 + half * 16];
        *(s16x8*)&gt[gb + 8] = *(const s16x8*)&S[GL + col * 40 + half * 16 + 8];
    }
}

// ------------------------------------------------------- flash attention
// (byte-identical to round 9's passing kernel)
__global__ __launch_bounds__(256, 2) void k_attn(
    const u16* __restrict__ th, const u16* __restrict__ ph,
    const u16* __restrict__ gt, u16* __restrict__ ot,
    float* __restrict__ Mv, float* __restrict__ Lv) {
    __shared__ u16 smem[17408];          // 34816 B (epilogue needs 128x136)
    u16* skh = smem;                     // 64 x 128 fp16, chunk16 ^= row&7
    u16* sg  = smem + 8192;              // 128 x 64 bf16, chunk16 ^= row&7
    int tid = threadIdx.x, w = tid >> 6, lane = tid & 63;
    int q = lane & 31, b = lane >> 5;
    int bb = blockIdx.y;
    int s = blockIdx.x & 1;              // interleaved: pairs share theta
    int qt = blockIdx.x >> 1;
    int n0 = qt * 128;
    int row128 = w * 32 + q;
    size_t qrow = ((size_t)bb * 4096 + n0 + row128) * 128;

    f16x8 Qf[8];
#pragma unroll
    for (int ks = 0; ks < 8; ks++)
        Qf[ks] = *(const f16x8*)&th[qrow + ks * 16 + b * 8];

    float mrow = -INFINITY, lrow = 0.f;
    f32x16 o[4];
#pragma unroll
    for (int c = 0; c < 4; c++) o[c] = (f32x16)0.f;

    int r_hi = lane >> 4, c_hi = lane & 15;
    int r_lo = lane >> 3, c_lo = lane & 7;
    int k0 = s * 1024;

    for (int kt = 0; kt < 16; kt++) {
        int m0 = k0 + kt * 64;
        if (kt) __syncthreads();
#pragma unroll
        for (int jj = 0; jj < 4; jj++) {
            int r = w * 16 + jj * 4 + r_hi;
            int gc = c_hi ^ (r & 7);
            size_t ga = (((size_t)(bb * 2048 + m0 + r)) << 7) + gc * 8;
            gload_lds16(&ph[ga], &skh[(w * 16 + jj * 4) << 7]);
            int r2 = w * 32 + jj * 8 + r_lo;
            int gc2 = c_lo ^ (r2 & 7);
            size_t ga2 = (size_t)bb * (128 * 2048) + (size_t)r2 * 2048 + m0 + gc2 * 8;
            gload_lds16(&gt[ga2], &sg[(w * 32 + jj * 8) << 6]);
        }
        __syncthreads();

        // S^T = phi . theta^T : single fp16 pass. D[key][query], col = q
        f32x16 S[2];
        S[0] = (f32x16)0.f; S[1] = (f32x16)0.f;
        __builtin_amdgcn_s_setprio(1);
#pragma unroll
        for (int ks = 0; ks < 8; ks++) {
            int off0 = (q << 7) + (((ks * 2 + b) ^ (q & 7)) << 3);
            int r1 = 32 + q;
            int off1 = (r1 << 7) + (((ks * 2 + b) ^ (r1 & 7)) << 3);
            f16x8 a0 = *(const f16x8*)&skh[off0];
            f16x8 a1 = *(const f16x8*)&skh[off1];
            S[0] = MFMA32F(a0, Qf[ks], S[0]);
            S[1] = MFMA32F(a1, Qf[ks], S[1]);
        }
        __builtin_amdgcn_s_setprio(0);

        // tree max (depth 5) + cross-half shuffle
        float t0[8];
#pragma unroll
        for (int r = 0; r < 8; r++)
            t0[r] = fmaxf(fmaxf(S[0][r], S[0][r + 8]),
                          fmaxf(S[1][r], S[1][r + 8]));
        float u0 = fmaxf(t0[0], t0[1]), u1 = fmaxf(t0[2], t0[3]);
        float u2 = fmaxf(t0[4], t0[5]), u3 = fmaxf(t0[6], t0[7]);
        float vmax = fmaxf(fmaxf(u0, u1), fmaxf(u2, u3));
        vmax = fmaxf(vmax, __shfl_xor(vmax, 32, 64));

        // deferred rescale (THR=20: P <= e^20, l <= 1024*e^20 -- f32 safe)
        if (!__all(vmax - mrow <= 20.f)) {
            float nm = fmaxf(mrow, vmax);
            float alph = __expf(mrow - nm);
            mrow = nm;
            lrow *= alph;
#pragma unroll
            for (int c = 0; c < 4; c++)
#pragma unroll
                for (int r = 0; r < 16; r++) o[c][r] *= alph;
        }
        float rs0 = 0.f, rs1 = 0.f, rs2 = 0.f, rs3 = 0.f;
#pragma unroll
        for (int r = 0; r < 4; r++) {
            float p00 = __expf(S[0][r] - mrow);      S[0][r] = p00;      rs0 += p00;
            float p01 = __expf(S[0][r + 4] - mrow);  S[0][r + 4] = p01;  rs1 += p01;
            float p02 = __expf(S[0][r + 8] - mrow);  S[0][r + 8] = p02;  rs2 += p02;
            float p03 = __expf(S[0][r + 12] - mrow); S[0][r + 12] = p03; rs3 += p03;
            float p10 = __expf(S[1][r] - mrow);      S[1][r] = p10;      rs0 += p10;
            float p11 = __expf(S[1][r + 4] - mrow);  S[1][r + 4] = p11;  rs1 += p11;
            float p12 = __expf(S[1][r + 8] - mrow);  S[1][r + 8] = p12;  rs2 += p12;
            float p13 = __expf(S[1][r + 12] - mrow); S[1][r + 12] = p13; rs3 += p13;
        }
        float rs = (rs0 + rs1) + (rs2 + rs3);
        rs += __shfl_xor(rs, 32, 64);
        lrow += rs;

        // P @ V: B-fragments packed straight from S D-regs (no LDS!)
        __builtin_amdgcn_s_setprio(1);
#pragma unroll
        for (int t = 0; t < 4; t++) {
            int half = t >> 1, base = (t & 1) * 8;
            s16x8 Pf;
            u32* pf = (u32*)&Pf;
#pragma unroll
            for (int r2 = 0; r2 < 4; r2++)
                pf[r2] = pkbf(S[half][base + 2 * r2], S[half][base + 2 * r2 + 1]);
#pragma unroll
            for (int c = 0; c < 4; c++) {
                int ch = c * 32 + q;
                int off = (ch << 6) + (((t * 2 + b) ^ (ch & 7)) << 3);
                s16x8 gv = *(const s16x8*)&sg[off];
                o[c] = MFMA32(gv, Pf, o[c]);
            }
        }
        __builtin_amdgcn_s_setprio(0);
    }
    __syncthreads();

    // epilogue: LDS transpose O^T[ch][q] -> [q][ch], store bf16 unnormalized
    u16* sc = smem;  // 128 x 136 u16 = 34816 B
#pragma unroll
    for (int c = 0; c < 4; c++)
#pragma unroll
        for (int r2 = 0; r2 < 8; r2++) {
            int ch = c * 32 + ((r2 & 1) << 1) + 8 * (r2 >> 1) + 4 * b;
            u32 pk = (u32)f2bf(o[c][2 * r2]) | ((u32)f2bf(o[c][2 * r2 + 1]) << 16);
            *(u32*)&sc[row128 * 136 + ch] = pk;
        }
    __syncthreads();
    size_t obase = ((size_t)s * 32768 + (size_t)bb * 4096 + n0) * 128;
    int rowy = tid >> 1;
#pragma unroll
    for (int j = 0; j < 8; j++) {
        int chk = (tid & 1) * 8 + j;
        s16x8 v = *(const s16x8*)&sc[rowy * 136 + chk * 8];
        *(s16x8*)&ot[obase + (size_t)rowy * 128 + chk * 8] = v;
    }
    if (b == 0) {
        int gi = s * 32768 + bb * 4096 + n0 + row128;
        Mv[gi] = mrow;
        Lv[gi] = lrow;
    }
}

// ------------- output GEMM + residual + split-K combine (single K pass)
// K=128 staged in one shot: sy/sw 128x128 u16 XOR-swizzled (chunk^=row&7,
// same pattern as k_attn; avoids +pad so both fit exactly 64 KB LDS).
// One 24-load burst (full MLP, one latency exposure), one barrier, 64 MFMA
// with hoisted fragments (LDS reads 80->32/wave), one barrier, transpose
// epilogue. Combine packs via pkbf truncation (1 op/2 elems).
__global__ __launch_bounds__(256) void k_out(
    const u16* __restrict__ ot, const float* __restrict__ Mv,
    const float* __restrict__ Lv, const u16* __restrict__ wot,
    const float* __restrict__ x, float* __restrict__ out) {
    __shared__ char lds_o[65536];
    u16 (*sy)[128] = (u16(*)[128])lds_o;
    u16 (*sw)[128] = (u16(*)[128])(lds_o + 32768);
    int tid = threadIdx.x, w = tid >> 6, lane = tid & 63, q = lane >> 4, li = lane & 15;
    int r0 = blockIdx.x * 128, c0 = blockIdx.y * 128;
    int wr = (w >> 1) * 64, wc = (w & 1) * 64;
    const size_t OS = (size_t)32768 * 128;

    int sr = tid >> 4;                   // base row 0..15
    int cc = (tid & 15) * 8;             // col base (8 elems)
    int swc = tid & 15;                  // chunk idx 0..15

    float a1v[8], a2v[8];
#pragma unroll
    for (int i = 0; i < 8; i++) {
        int gr = r0 + sr + i * 16;
        float m1 = Mv[gr], m2 = Mv[32768 + gr];
        float l1 = Lv[gr], l2 = Lv[32768 + gr];
        float Mx = fmaxf(m1, m2);
        float e1 = __expf(m1 - Mx), e2 = __expf(m2 - Mx);
        float inv = 1.f / (l1 * e1 + l2 * e2);
        a1v[i] = e1 * inv;
        a2v[i] = e2 * inv;
    }

    // stage: combine 2 splits -> bf16 (pkbf truncate), swizzled LDS write
#pragma unroll
    for (int i = 0; i < 8; i++) {
        int r = sr + i * 16;
        size_t ga = (size_t)(r0 + r) * 128 + cc;
        s16x8 o1 = *(const s16x8*)&ot[ga];
        s16x8 o2 = *(const s16x8*)&ot[OS + ga];
        u32 yv[4];
#pragma unroll
        for (int e = 0; e < 4; e++) {
            float v0 = bf2f((u16)o1[2 * e])     * a1v[i] + bf2f((u16)o2[2 * e])     * a2v[i];
            float v1 = bf2f((u16)o1[2 * e + 1]) * a1v[i] + bf2f((u16)o2[2 * e + 1]) * a2v[i];
            yv[e] = pkbf(v0, v1);
        }
        int sc2 = (swc ^ (r & 7)) * 8;
        *(s16x8*)&sy[r][sc2] = *(const s16x8*)&yv[0];
        *(s16x8*)&sw[r][sc2] = *(const s16x8*)&wot[(size_t)(c0 + r) * 128 + cc];
    }
    __syncthreads();

    f32x4 acc[4][4];
#pragma unroll
    for (int i = 0; i < 4; i++)
#pragma unroll
        for (int j = 0; j < 4; j++) acc[i][j] = (f32x4)0.f;

#pragma unroll
    for (int ks = 0; ks < 4; ks++) {
        s16x8 av[4], bv[4];
#pragma unroll
        for (int i = 0; i < 4; i++) {
            int ar = wr + i * 16 + li;
            av[i] = *(const s16x8*)&sy[ar][((ks * 4 + q) ^ (ar & 7)) * 8];
            int br = wc + i * 16 + li;
            bv[i] = *(const s16x8*)&sw[br][((ks * 4 + q) ^ (br & 7)) * 8];
        }
#pragma unroll
        for (int i = 0; i < 4; i++)
#pragma unroll
            for (int j = 0; j < 4; j++)
                acc[i][j] = MFMA(av[i], bv[j], acc[i][j]);
    }

    // float4 epilogue via LDS transpose, 2 chunks of 64 rows
    float* sT = (float*)lds_o;           // 64 x 132 f32 = 33792 B
#pragma unroll
    for (int h = 0; h < 2; h++) {
        __syncthreads();
        if ((w >> 1) == h) {
#pragma unroll
            for (int i = 0; i < 4; i++)
#pragma unroll
                for (int j = 0; j < 4; j++)
#pragma unroll
                    for (int reg = 0; reg < 4; reg++)
                        sT[(i * 16 + q * 4 + reg) * 132 + wc + j * 16 + li] =
                            acc[i][j][reg];
        }
        __syncthreads();
#pragma unroll
        for (int p = 0; p < 8; p++) {
            int r = (tid >> 5) + p * 8;
            int c4 = (tid & 31) * 4;
            f32x4 yv = *(f32x4*)&sT[r * 132 + c4];
            size_t row = (size_t)(r0 + h * 64 + r);
            float4 xv = *(const float4*)&x[row * 256 + c0 + c4];
            float4 ov;
            ov.x = xv.x + yv[0]; ov.y = xv.y + yv[1];
            ov.z = xv.z + yv[2]; ov.w = xv.w + yv[3];
            *(float4*)&out[row * 256 + c0 + c4] = ov;
        }
    }
}

// ---------------------------------------------------------------- launch
extern "C" void kernel_launch(void* const* d_in, const int* in_sizes, int n_in,
                              void* d_out, int out_size, void* d_ws, size_t ws_size,
                              hipStream_t stream) {
    const float* x  = (const float*)d_in[0];
    const float* wt = (const float*)d_in[1];
    const float* wp = (const float*)d_in[2];
    const float* wg = (const float*)d_in[3];
    const float* wo = (const float*)d_in[4];
    float* out = (float*)d_out;

    char* p = (char*)d_ws;
    auto alloc = [&](size_t bytes) {
        char* r = p;
        p += (bytes + 255) & ~(size_t)255;
        return r;
    };
    const size_t NT = (size_t)BB * NN * CBD;   // 4194304
    const size_t NP = (size_t)BB * MM * CBD;   // 2097152

    u16* wtf = (u16*)alloc(CC * CBD * 2);      // fp16 W_theta^T
    u16* wpf = (u16*)alloc(CC * CBD * 2);      // fp16 W_phi^T
    u16* wgf = (u16*)alloc(CC * CBD * 2);      // fp16 W_g^T
    u16* wot = (u16*)alloc(CC * CBD * 2);      // bf16 W_out^T
    u16* th  = (u16*)alloc(NT * 2);            // fp16 theta
    u16* ph  = (u16*)alloc(NP * 2);            // fp16 pooled phi
    u16* gt  = (u16*)alloc(NP * 2);            // bf16 pooled g (PV perm)
    float* Mv = (float*)alloc(2 * 32768 * 4);
    float* Lv = (float*)alloc(2 * 32768 * 4);
    u16* ot  = (u16*)alloc(2 * NT * 2);        // [2][32768][128] bf16

    k_split_w<<<dim3(128, 4), 256, 0, stream>>>(wt, wp, wg, wo,
                                                wtf, wpf, wgf, wot);
    k_proj<<<dim3(512), 256, 0, stream>>>(x, wtf, wpf, wgf, th, ph, gt);
    k_attn<<<dim3(64, 8), 256, 0, stream>>>(th, ph, gt, ot, Mv, Lv);
    k_out<<<dim3(256, 2), 256, 0, stream>>>(ot, Mv, Lv, wot, x, out);
}